// Round 17
// baseline (322.734 us; speedup 1.0000x reference)
//
#include <hip/hip_runtime.h>
#include <hip/hip_fp16.h>

// AttentionBlock3D: channel attention. B=4, C=512, N=T*H*W=16384, 8 heads, d=64.
// Algebraic reduction: result = x + M*H + c, with
//   G = H H^T (per batch, SYMMETRIC -> upper tiles + mirror),
//   logits = scale*(Wq G Wk^T + rank-1), P = softmax per head,
//   M = out_w * blockdiag(P) * Wv, c = out_w * blockdiag(P) * bv + out_b.
//
// MFMA geometry LOCKED (R9): BK=64, 128B rows, XOR-swizzle slot^(row&7) (0 bank
//   conflicts), single 32KB LDS buffer, 2 barriers/K-step, lb(256,2).
//   k_out plateau 84-85us over 7 variants -> closed.
// R13: fp16 MFMA GEMMs w/ G16 = fp16(G-16384*I) + exact fp32 rank-shift restore.
// R15: fused k_attn (logits MFMA + softmax + PV MFMA). 359 -> 303us.
// R17: launch-count reduction. k_prep = stats+cast(qkvw,outw)+wvt (independent,
//   concurrent). k_mid = symm -> hgemm(T1) -> attn -> hgemm(M) -> cvec in ONE
//   64-block kernel with software grid barriers (agent-scope release/acquire;
//   bar[] zeroed by the graph's memset each replay; 64 blocks always co-resident).

#define CCH 512
#define NTOK 16384
#define NHEAD 8

typedef _Float16 f16;
typedef _Float16 f16x8 __attribute__((ext_vector_type(8)));
typedef float f32x4 __attribute__((ext_vector_type(4)));

__device__ __forceinline__ void g2l16(const void* g, void* l) {
  __builtin_amdgcn_global_load_lds((const __attribute__((address_space(1))) void*)g,
                                   (__attribute__((address_space(3))) void*)l,
                                   16, 0, 0);
}

// software grid barrier: all blocks call with same id; bar[id] pre-zeroed.
__device__ __forceinline__ void gbar(int* bar, int id, int nblk) {
  __syncthreads();
  if (threadIdx.x == 0) {
    __hip_atomic_fetch_add(&bar[id], 1, __ATOMIC_RELEASE, __HIP_MEMORY_SCOPE_AGENT);
    while (__hip_atomic_load(&bar[id], __ATOMIC_ACQUIRE, __HIP_MEMORY_SCOPE_AGENT) < nblk)
      __builtin_amdgcn_s_sleep(2);
  }
  __syncthreads();
}

// ---------------- K1: prep = GN stats + fp16 casts + Wv transpose (one launch) ----
// blocks [0,1024): stats; [1024,1792): cast qkvw; [1792,2048): cast outw;
// [2048,2112): Wvt16[c][e] = fp16(qkvw[1024+e][c]).
__global__ __launch_bounds__(256) void k_prep(const float* __restrict__ x,
                                              float* __restrict__ stats,
                                              const float* __restrict__ qkvw,
                                              f16* __restrict__ Wqkv16,
                                              const float* __restrict__ outw,
                                              f16* __restrict__ Ow16,
                                              f16* __restrict__ Wvt16) {
  __shared__ __align__(16) char smp[9216];
  int bid = blockIdx.x;
  int t = threadIdx.x;
  if (bid < 1024) {                      // ---- GN stats ----
    int chunk = bid & 31, bg = bid >> 5;
    const float4* p = (const float4*)(x + (size_t)bg * (64ull * NTOK)) + (size_t)chunk * 8192;
    float s = 0.f, q = 0.f;
    for (int i = t; i < 8192; i += 256) {
      float4 v = p[i];
      s += v.x + v.y + v.z + v.w;
      q += v.x * v.x + v.y * v.y + v.z * v.z + v.w * v.w;
    }
    for (int off = 32; off; off >>= 1) { s += __shfl_down(s, off); q += __shfl_down(q, off); }
    float* ls = (float*)smp; float* lq = ls + 4;
    int wid = t >> 6, lane = t & 63;
    if (lane == 0) { ls[wid] = s; lq[wid] = q; }
    __syncthreads();
    if (t == 0) {
      atomicAdd(&stats[bg * 2 + 0], ls[0] + ls[1] + ls[2] + ls[3]);
      atomicAdd(&stats[bg * 2 + 1], lq[0] + lq[1] + lq[2] + lq[3]);
    }
  } else if (bid < 2048) {               // ---- fp32->fp16 casts ----
    bool isB = bid >= 1792;
    int i = (isB ? (bid - 1792) : (bid - 1024)) * 256 + t;
    const float* src = isB ? outw : qkvw;
    f16* dst = isB ? Ow16 : Wqkv16;
    float4 v = *(const float4*)&src[i * 4];
    f16 h[4] __attribute__((aligned(8)));
    h[0] = (f16)v.x; h[1] = (f16)v.y; h[2] = (f16)v.z; h[3] = (f16)v.w;
    *(uint2*)&dst[i * 4] = *(const uint2*)h;
  } else {                               // ---- Wv transpose-cast ----
    int j = bid - 2048;
    int et = j >> 3, ct = j & 7;
    f16 (*tl)[72] = (f16(*)[72])smp;
    int r = t >> 2, cq = (t & 3) * 16;
    const float* src = &qkvw[(size_t)(1024 + et * 64 + r) * CCH + ct * 64 + cq];
#pragma unroll
    for (int k = 0; k < 4; ++k) {
      float4 v = *(const float4*)(src + k * 4);
      tl[r][cq + k * 4 + 0] = (f16)v.x; tl[r][cq + k * 4 + 1] = (f16)v.y;
      tl[r][cq + k * 4 + 2] = (f16)v.z; tl[r][cq + k * 4 + 3] = (f16)v.w;
    }
    __syncthreads();
    f16 hv[16] __attribute__((aligned(16)));
#pragma unroll
    for (int jj = 0; jj < 16; ++jj) hv[jj] = tl[cq + jj][r];
    f16* dst = &Wvt16[(size_t)(ct * 64 + r) * CCH + et * 64 + cq];
    *(uint4*)&dst[0] = ((const uint4*)hv)[0];
    *(uint4*)&dst[8] = ((const uint4*)hv)[1];
  }
}

// ---------------- K2: normalize -> H (fp16 [b][c][n]), Ht (fp16 [b][n][c]), svec ----
__global__ __launch_bounds__(256) void k_gnorm(const float* __restrict__ x,
                                               const float* __restrict__ gw,
                                               const float* __restrict__ gb,
                                               const float* __restrict__ stats,
                                               f16* __restrict__ H, f16* __restrict__ Ht,
                                               float* __restrict__ svec) {
  int nc = blockIdx.x;   // n chunk (256 tokens)
  int cg = blockIdx.y;   // channel group (64 ch) == GN group
  int b = blockIdx.z;
  int t = threadIdx.x;
  __shared__ f16 T2[64][260];
  __shared__ float svp[4][64];
  float sum = stats[(b * 8 + cg) * 2], sq = stats[(b * 8 + cg) * 2 + 1];
  const float inv = 1.f / (64.f * (float)NTOK);
  float mean = sum * inv;
  float var = fmaxf(sq * inv - mean * mean, 0.f);
  float rsig = rsqrtf(var + 1e-5f);
  int c0 = cg * 64, n0 = nc * 256;
  int tq = t & 63, rr0 = t >> 6;
#pragma unroll
  for (int it = 0; it < 16; ++it) {
    int r = it * 4 + rr0;
    int c = c0 + r;
    float a = gw[c] * rsig;
    float bb = gb[c] - mean * a;
    size_t idx = ((size_t)(b * CCH + c)) * NTOK + n0 + tq * 4;
    float4 xv = *(const float4*)&x[idx];
    f16 hh[4] __attribute__((aligned(8)));
    hh[0] = (f16)(xv.x * a + bb);
    hh[1] = (f16)(xv.y * a + bb);
    hh[2] = (f16)(xv.z * a + bb);
    hh[3] = (f16)(xv.w * a + bb);
    *(uint2*)&H[idx] = *(const uint2*)hh;
    *(uint2*)&T2[r][tq * 4] = *(const uint2*)hh;
  }
  __syncthreads();
  {
    int c = t & 63, q = t >> 6;
    float acc = 0.f;
#pragma unroll
    for (int j = 0; j < 64; ++j) acc += (float)T2[c][q * 64 + j];
    svp[q][c] = acc;
  }
  __syncthreads();
  if (t < 64) {
    atomicAdd(&svec[b * CCH + c0 + t],
              svp[0][t] + svp[1][t] + svp[2][t] + svp[3][t]);
  }
  int s8 = t & 7, nl = t >> 3;
#pragma unroll
  for (int it = 0; it < 8; ++it) {
    int n = it * 32 + nl;
    f16 g[8] __attribute__((aligned(16)));
#pragma unroll
    for (int j = 0; j < 8; ++j) g[j] = T2[s8 * 8 + j][n];
    *(uint4*)&Ht[((size_t)b * NTOK + n0 + n) * CCH + c0 + s8 * 8] = *(const uint4*)g;
  }
}

// ---------------- K3: G = H H^T, upper tiles, split-K=16, BK=64 single-buf (32KB) ----
#define SPLITS 16
__global__ __launch_bounds__(256, 2) void k_syrk(const f16* __restrict__ H,
                                                 float* __restrict__ G) {
  const int TI[10] = {0, 0, 0, 0, 1, 1, 1, 2, 2, 3};
  const int TJ[10] = {0, 1, 2, 3, 1, 2, 3, 2, 3, 3};
  int tile = blockIdx.x;
  int split = blockIdx.y;
  int b = blockIdx.z;
  int ii = TI[tile], jj = TJ[tile];
  int m0 = ii * 128, n0 = jj * 128;
  int t = threadIdx.x, lane = t & 63, wid = t >> 6;
  int wr = wid >> 1, wc = wid & 1;
  __shared__ __align__(16) f16 sA[128 * 64];
  __shared__ __align__(16) f16 sB[128 * 64];
  const f16* Hb = H + (size_t)b * CCH * NTOK;
  int k0 = split * (NTOK / SPLITS);
  f32x4 acc[4][4] = {};
  int ldsrow = wid * 8 + (lane >> 3);
  int slot = lane & 7;
  int lr = lane & 15, lk = lane >> 4;

  const int NS = (NTOK / SPLITS) / 64;
  for (int ks = 0; ks < NS; ++ks) {
    int kk0 = k0 + ks * 64;
    __syncthreads();
#pragma unroll
    for (int i = 0; i < 4; ++i) {
      int row = ldsrow + i * 32;
      int cA = ((slot ^ (row & 7)) * 8);
      g2l16(Hb + (size_t)(m0 + row) * NTOK + kk0 + cA, &sA[i * 2048 + wid * 512]);
      g2l16(Hb + (size_t)(n0 + row) * NTOK + kk0 + cA, &sB[i * 2048 + wid * 512]);
    }
    asm volatile("s_waitcnt vmcnt(0)" ::: "memory");
    __syncthreads();
#pragma unroll
    for (int kk = 0; kk < 2; ++kk) {
      f16x8 af[4], bf[4];
#pragma unroll
      for (int mi = 0; mi < 4; ++mi) {
        int row = wr * 64 + mi * 16 + lr;
        int ks8 = (kk * 4 + lk) ^ (row & 7);
        af[mi] = *(const f16x8*)&sA[row * 64 + ks8 * 8];
      }
#pragma unroll
      for (int ni = 0; ni < 4; ++ni) {
        int row = wc * 64 + ni * 16 + lr;
        int ks8 = (kk * 4 + lk) ^ (row & 7);
        bf[ni] = *(const f16x8*)&sB[row * 64 + ks8 * 8];
      }
#pragma unroll
      for (int mi = 0; mi < 4; ++mi)
#pragma unroll
        for (int ni = 0; ni < 4; ++ni)
          acc[mi][ni] = __builtin_amdgcn_mfma_f32_16x16x32_f16(af[mi], bf[ni], acc[mi][ni], 0, 0, 0);
    }
  }

  float* Gb = G + (size_t)b * CCH * CCH;
#pragma unroll
  for (int mi = 0; mi < 4; ++mi)
#pragma unroll
    for (int j = 0; j < 4; ++j) {
      int rr2 = m0 + wr * 64 + mi * 16 + lk * 4 + j;
#pragma unroll
      for (int ni = 0; ni < 4; ++ni) {
        int cc = n0 + wc * 64 + ni * 16 + lr;
        atomicAdd(&Gb[(size_t)rr2 * CCH + cc], acc[mi][ni][j]);
      }
    }
}

// ---------------- device body: fp16 MFMA 128x128 tile of C[b] = A16 @ Bt16[b]^T ----
template <bool CORR>
__device__ __forceinline__ void hgemm_tile(const f16* __restrict__ A16,
                                           const f16* __restrict__ Bt16,
                                           f16* __restrict__ Cv,
                                           const float* __restrict__ corr,
                                           int m0, int n0, int b, char* sm) {
  int t = threadIdx.x, lane = t & 63, wid = t >> 6;
  int wr = wid >> 1, wc = wid & 1;
  f16* sA = (f16*)sm;
  f16* sB = (f16*)(sm + 16384);
  const f16* Bp = Bt16 + (size_t)b * CCH * CCH;
  f32x4 acc[4][4] = {};
  int ldsrow = wid * 8 + (lane >> 3);
  int slot = lane & 7;
  int lr = lane & 15, lk = lane >> 4;
  for (int ks = 0; ks < 8; ++ks) {
    int kk0 = ks * 64;
    __syncthreads();
#pragma unroll
    for (int i = 0; i < 4; ++i) {
      int row = ldsrow + i * 32;
      int cA = ((slot ^ (row & 7)) * 8);
      g2l16(A16 + (size_t)(m0 + row) * CCH + kk0 + cA, &sA[i * 2048 + wid * 512]);
      g2l16(Bp + (size_t)(n0 + row) * CCH + kk0 + cA, &sB[i * 2048 + wid * 512]);
    }
    asm volatile("s_waitcnt vmcnt(0)" ::: "memory");
    __syncthreads();
#pragma unroll
    for (int kk = 0; kk < 2; ++kk) {
      f16x8 af[4], bf[4];
#pragma unroll
      for (int mi = 0; mi < 4; ++mi) {
        int row = wr * 64 + mi * 16 + lr;
        int ks8 = (kk * 4 + lk) ^ (row & 7);
        af[mi] = *(const f16x8*)&sA[row * 64 + ks8 * 8];
      }
#pragma unroll
      for (int ni = 0; ni < 4; ++ni) {
        int row = wc * 64 + ni * 16 + lr;
        int ks8 = (kk * 4 + lk) ^ (row & 7);
        bf[ni] = *(const f16x8*)&sB[row * 64 + ks8 * 8];
      }
#pragma unroll
      for (int mi = 0; mi < 4; ++mi)
#pragma unroll
        for (int ni = 0; ni < 4; ++ni)
          acc[mi][ni] = __builtin_amdgcn_mfma_f32_16x16x32_f16(af[mi], bf[ni], acc[mi][ni], 0, 0, 0);
    }
  }
#pragma unroll
  for (int mi = 0; mi < 4; ++mi)
#pragma unroll
    for (int j = 0; j < 4; ++j) {
      int o = m0 + wr * 64 + mi * 16 + lk * 4 + j;
#pragma unroll
      for (int ni = 0; ni < 4; ++ni) {
        int n = n0 + wc * 64 + ni * 16 + lr;
        float v = acc[mi][ni][j];
        if constexpr (CORR) v += 16384.f * corr[(size_t)o * CCH + n];
        Cv[(size_t)b * CCH * CCH + (size_t)o * CCH + n] = (f16)v;
      }
    }
}

// ---------------- K4: fused middle chain (64 blocks, software grid barriers) -------
// P0 symm+cast G->G16 | P1 T1h = Wq@G16 (+16384*Wq) | P2 per-(b,h) attention
// | P3 M16 = Ow@Rt16 | P4 cvec. Bodies verified as standalone kernels (R13-R15).
__global__ __launch_bounds__(256) void k_mid(float* __restrict__ G,
                                             f16* __restrict__ G16,
                                             const f16* __restrict__ Wqkv16,
                                             f16* __restrict__ T1h,
                                             const float* __restrict__ qkvw,
                                             const float* __restrict__ qkvb,
                                             const float* __restrict__ svec,
                                             const f16* __restrict__ Wvt16,
                                             f16* __restrict__ Rt16,
                                             float* __restrict__ pbv,
                                             const f16* __restrict__ Ow16,
                                             f16* __restrict__ M16,
                                             const float* __restrict__ outw,
                                             const float* __restrict__ outb,
                                             float* __restrict__ cvec,
                                             int* __restrict__ bar, int B) {
  __shared__ __align__(16) char sm[32768];
  const int NB = 64;
  int bid = blockIdx.x;
  int t = threadIdx.x;

  // ---------- P0: mirror off-diag + cast G -> G16 (G16 = fp16(G - 16384*I)) -------
  {
    const int TI6[6] = {0, 0, 0, 1, 1, 2};
    const int TJ6[6] = {1, 2, 3, 2, 3, 3};
    float (*s)[65] = (float(*)[65])sm;
    int r = t >> 2, cg = (t & 3) * 16;
    for (int it = bid; it < 40 * B; it += NB) {
      int bx = it % 40, b = it / 40;
      float* Gb = G + (size_t)b * CCH * CCH;
      f16* Gh = G16 + (size_t)b * CCH * CCH;
      int ib, jb;
      bool mirror = bx < 24;
      if (mirror) {
        int t6 = bx >> 2, sub = bx & 3;
        ib = TI6[t6] * 2 + (sub >> 1); jb = TJ6[t6] * 2 + (sub & 1);
      } else {
        int idx = bx - 24; int dt = idx >> 2, sub = idx & 3;
        ib = dt * 2 + (sub >> 1); jb = dt * 2 + (sub & 1);
      }
      int grow = ib * 64 + r, gcol0 = jb * 64 + cg;
      const float* src = &Gb[(size_t)grow * CCH + gcol0];
      f16 hv[16] __attribute__((aligned(16)));
#pragma unroll
      for (int k = 0; k < 4; ++k) {
        float4 v = *(const float4*)(src + k * 4);
        if (mirror) {
          s[r][cg + k * 4 + 0] = v.x; s[r][cg + k * 4 + 1] = v.y;
          s[r][cg + k * 4 + 2] = v.z; s[r][cg + k * 4 + 3] = v.w;
        }
        hv[k * 4 + 0] = (f16)(v.x - ((grow == gcol0 + k * 4 + 0) ? 16384.f : 0.f));
        hv[k * 4 + 1] = (f16)(v.y - ((grow == gcol0 + k * 4 + 1) ? 16384.f : 0.f));
        hv[k * 4 + 2] = (f16)(v.z - ((grow == gcol0 + k * 4 + 2) ? 16384.f : 0.f));
        hv[k * 4 + 3] = (f16)(v.w - ((grow == gcol0 + k * 4 + 3) ? 16384.f : 0.f));
      }
      f16* d16 = &Gh[(size_t)grow * CCH + gcol0];
      *(uint4*)&d16[0] = ((const uint4*)hv)[0];
      *(uint4*)&d16[8] = ((const uint4*)hv)[1];
      if (mirror) {
        __syncthreads();
        float* dst = &Gb[(size_t)(jb * 64 + r) * CCH + ib * 64 + cg];
        f16 hw[16] __attribute__((aligned(16)));
#pragma unroll
        for (int k = 0; k < 4; ++k) {
          float4 v;
          v.x = s[cg + k * 4 + 0][r]; v.y = s[cg + k * 4 + 1][r];
          v.z = s[cg + k * 4 + 2][r]; v.w = s[cg + k * 4 + 3][r];
          *(float4*)(dst + k * 4) = v;
          hw[k * 4 + 0] = (f16)v.x; hw[k * 4 + 1] = (f16)v.y;
          hw[k * 4 + 2] = (f16)v.z; hw[k * 4 + 3] = (f16)v.w;
        }
        f16* m16p = &Gh[(size_t)(jb * 64 + r) * CCH + ib * 64 + cg];
        *(uint4*)&m16p[0] = ((const uint4*)hw)[0];
        *(uint4*)&m16p[8] = ((const uint4*)hw)[1];
      }
      __syncthreads();   // LDS reuse across loop iterations
    }
  }
  gbar(bar, 0, NB);

  // ---------- P1: T1h = fp16(Wq @ G + 16384*Wq), B-operand = G16 (symmetry) -------
  {
    int n0 = (bid & 3) * 128, m0 = ((bid >> 2) & 3) * 128, b = bid >> 4;
    hgemm_tile<true>(Wqkv16, G16, T1h, qkvw, m0, n0, b, sm);
  }
  gbar(bar, 1, NB);

  // ---------- P2: per-(b,h) attention (blocks 0..8B-1) ----------
  if (bid < NHEAD * B) {
    int h = bid & 7, b = bid >> 3;
    int h64 = h * 64;
    int lane = t & 63, wid = t >> 6;
    int lr = lane & 15, lk = lane >> 4;
    float* ss = (float*)sm;                          // 512 f
    float* suq = ss + 512;                           // 64
    float* suk = suq + 64;
    float* sbq = suk + 64;
    float* sbk = sbq + 64;
    float* sbv = sbk + 64;                           // ends at 832 f = 3328 B
    float (*Lsm)[68] = (float(*)[68])(sm + 3328);    // 17408 B
    f16 (*Psm)[72] = (f16(*)[72])(sm + 3328 + 17408);  // 9216 B -> total 29952

    for (int i = t; i < 512; i += 256) ss[i] = svec[b * CCH + i];
    if (t < 64) {
      sbq[t] = qkvb[h64 + t];
      sbk[t] = qkvb[512 + h64 + t];
      sbv[t] = qkvb[1024 + h64 + t];
    }
    __syncthreads();
    if (t < 128) {
      int o = t & 63; bool isk = t >= 64;
      const float* wr_ = qkvw + (size_t)((isk ? 512 : 0) + h64 + o) * CCH;
      float a = 0.f;
#pragma unroll
      for (int i = 0; i < 128; ++i) {
        float4 w = *(const float4*)&wr_[i * 4];
        a += w.x * ss[i * 4] + w.y * ss[i * 4 + 1] + w.z * ss[i * 4 + 2] + w.w * ss[i * 4 + 3];
      }
      (isk ? suk : suq)[o] = a;
    }
    int wr = wid >> 1, wc = wid & 1;
    f32x4 lacc[2][2] = {};
    const f16* Ab = T1h + (size_t)b * CCH * CCH;
    const f16* Bb = Wqkv16 + (size_t)(512 + h64) * CCH;
    for (int ks = 0; ks < 16; ++ks) {
      int kq = ks * 32 + lk * 8;
      f16x8 af[2], bf[2];
#pragma unroll
      for (int mi = 0; mi < 2; ++mi)
        af[mi] = *(const f16x8*)&Ab[(size_t)(h64 + wr * 32 + mi * 16 + lr) * CCH + kq];
#pragma unroll
      for (int ni = 0; ni < 2; ++ni)
        bf[ni] = *(const f16x8*)&Bb[(size_t)(wc * 32 + ni * 16 + lr) * CCH + kq];
#pragma unroll
      for (int mi = 0; mi < 2; ++mi)
#pragma unroll
        for (int ni = 0; ni < 2; ++ni)
          lacc[mi][ni] = __builtin_amdgcn_mfma_f32_16x16x32_f16(af[mi], bf[ni], lacc[mi][ni], 0, 0, 0);
    }
    __syncthreads();
#pragma unroll
    for (int mi = 0; mi < 2; ++mi)
#pragma unroll
      for (int ni = 0; ni < 2; ++ni)
#pragma unroll
        for (int j = 0; j < 4; ++j) {
          int d = wr * 32 + mi * 16 + lk * 4 + j;
          int e = wc * 32 + ni * 16 + lr;
          Lsm[d][e] = (lacc[mi][ni][j] + suq[d] * sbk[e] + sbq[d] * suk[e]
                       + 16384.f * sbq[d] * sbk[e]) * 0.125f;
        }
    __syncthreads();
    if (t < 64) {
      float m = -1e30f;
#pragma unroll
      for (int e = 0; e < 64; ++e) m = fmaxf(m, Lsm[t][e]);
      float p[64];
      float sum = 0.f;
#pragma unroll
      for (int e = 0; e < 64; ++e) { p[e] = expf(Lsm[t][e] - m); sum += p[e]; }
      float r = 1.f / sum, pb = 0.f;
#pragma unroll
      for (int e = 0; e < 64; ++e) {
        float pv = p[e] * r;
        Psm[t][e] = (f16)pv;
        pb += pv * sbv[e];
      }
      pbv[b * CCH + h64 + t] = pb;
    }
    __syncthreads();
    f32x4 acc[4][8] = {};
    int c0w = wid * 128;
#pragma unroll
    for (int kk = 0; kk < 2; ++kk) {
      int e0 = kk * 32 + lk * 8;
      f16x8 pa[4], wb[8];
#pragma unroll
      for (int mi = 0; mi < 4; ++mi)
        pa[mi] = *(const f16x8*)&Psm[mi * 16 + lr][e0];
#pragma unroll
      for (int ni = 0; ni < 8; ++ni)
        wb[ni] = *(const f16x8*)&Wvt16[(size_t)(c0w + ni * 16 + lr) * CCH + h64 + e0];
#pragma unroll
      for (int mi = 0; mi < 4; ++mi)
#pragma unroll
        for (int ni = 0; ni < 8; ++ni)
          acc[mi][ni] = __builtin_amdgcn_mfma_f32_16x16x32_f16(pa[mi], wb[ni], acc[mi][ni], 0, 0, 0);
    }
#pragma unroll
    for (int mi = 0; mi < 4; ++mi)
#pragma unroll
      for (int ni = 0; ni < 8; ++ni) {
        int d0 = mi * 16 + lk * 4;
        int c = c0w + ni * 16 + lr;
        f16 hv[4] __attribute__((aligned(8)));
#pragma unroll
        for (int j = 0; j < 4; ++j) hv[j] = (f16)acc[mi][ni][j];
        *(uint2*)&Rt16[((size_t)b * CCH + c) * CCH + h64 + d0] = *(const uint2*)hv;
      }
  }
  gbar(bar, 2, NB);

  // ---------- P3: M16 = Ow @ R (B-operand = Rt16, pre-transposed) ----------
  {
    int n0 = (bid & 3) * 128, m0 = ((bid >> 2) & 3) * 128, b = bid >> 4;
    hgemm_tile<false>(Ow16, Rt16, M16, nullptr, m0, n0, b, sm);
  }
  gbar(bar, 3, NB);

  // ---------- P4: cvec = out_w @ pbv + out_b (blocks 0..8B-1) ----------
  if (bid < 8 * B) {
    int ob = bid & 7, b = bid >> 3;
    float* sp = (float*)sm;
    for (int i = t; i < 512; i += 256) sp[i] = pbv[b * CCH + i];
    __syncthreads();
    int o = ob * 64 + (t >> 2);
    int l = t & 3;
    const float* wr_ = outw + (size_t)o * CCH + l * 128;
    const float* spp = sp + l * 128;
    float a = 0.f;
#pragma unroll
    for (int i = 0; i < 32; ++i) {
      float4 w = *(const float4*)&wr_[i * 4];
      a += w.x * spp[i * 4] + w.y * spp[i * 4 + 1] + w.z * spp[i * 4 + 2] + w.w * spp[i * 4 + 3];
    }
    a += __shfl_down(a, 2);
    a += __shfl_down(a, 1);
    if (l == 0) cvec[b * CCH + o] = a + outb[o];
  }
}

// ---------------- K5: out = x + M16 @ H + cvec (fp16 MFMA, transposed fragment) ----
__global__ __launch_bounds__(256, 2) void k_out(const f16* __restrict__ M16,
                                                const f16* __restrict__ Ht,
                                                const float* __restrict__ x,
                                                const float* __restrict__ cvec,
                                                float* __restrict__ out) {
  int nt = blockIdx.x;   // 128 n-tiles
  int mt = blockIdx.y;   // 4 o-tiles
  int b = blockIdx.z;
  int m0 = mt * 128, n0 = nt * 128;
  int t = threadIdx.x, lane = t & 63, wid = t >> 6;
  int wr = wid >> 1, wc = wid & 1;
  __shared__ __align__(16) f16 sA[128 * 64];
  __shared__ __align__(16) f16 sB[128 * 64];
  const f16* A = M16 + (size_t)b * CCH * CCH;
  const f16* Bp = Ht + (size_t)b * NTOK * CCH;
  f32x4 acc[4][4] = {};
  int ldsrow = wid * 8 + (lane >> 3);
  int slot = lane & 7;
  int lr = lane & 15, lk = lane >> 4;
  for (int ks = 0; ks < 8; ++ks) {
    int kk0 = ks * 64;
    __syncthreads();
#pragma unroll
    for (int i = 0; i < 4; ++i) {
      int row = ldsrow + i * 32;
      int cA = ((slot ^ (row & 7)) * 8);
      g2l16(A + (size_t)(m0 + row) * CCH + kk0 + cA, &sA[i * 2048 + wid * 512]);
      g2l16(Bp + (size_t)(n0 + row) * CCH + kk0 + cA, &sB[i * 2048 + wid * 512]);
    }
    asm volatile("s_waitcnt vmcnt(0)" ::: "memory");
    __syncthreads();
#pragma unroll
    for (int kk = 0; kk < 2; ++kk) {
      f16x8 af[4], bf[4];
#pragma unroll
      for (int mi = 0; mi < 4; ++mi) {
        int row = wr * 64 + mi * 16 + lr;
        int ks8 = (kk * 4 + lk) ^ (row & 7);
        af[mi] = *(const f16x8*)&sA[row * 64 + ks8 * 8];
      }
#pragma unroll
      for (int ni = 0; ni < 4; ++ni) {
        int row = wc * 64 + ni * 16 + lr;
        int ks8 = (kk * 4 + lk) ^ (row & 7);
        bf[ni] = *(const f16x8*)&sB[row * 64 + ks8 * 8];
      }
#pragma unroll
      for (int mi = 0; mi < 4; ++mi)
#pragma unroll
        for (int ni = 0; ni < 4; ++ni)   // swapped: D[n][o] fragment
          acc[mi][ni] = __builtin_amdgcn_mfma_f32_16x16x32_f16(bf[ni], af[mi], acc[mi][ni], 0, 0, 0);
    }
  }

  const float* xb = x + ((size_t)b * CCH) * NTOK;
  float* ob = out + ((size_t)b * CCH) * NTOK;
#pragma unroll
  for (int mi = 0; mi < 4; ++mi) {
    int o = m0 + wr * 64 + mi * 16 + lr;
    float cv = cvec[b * CCH + o];
    size_t rowoff = (size_t)o * NTOK;
#pragma unroll
    for (int ni = 0; ni < 4; ++ni) {
      int n = n0 + wc * 64 + ni * 16 + lk * 4;
      float4 xv = *(const float4*)&xb[rowoff + n];
      float4 ov;
      ov.x = xv.x + acc[mi][ni][0] + cv;
      ov.y = xv.y + acc[mi][ni][1] + cv;
      ov.z = xv.z + acc[mi][ni][2] + cv;
      ov.w = xv.w + acc[mi][ni][3] + cv;
      *(float4*)&ob[rowoff + n] = ov;
    }
  }
}

extern "C" void kernel_launch(void* const* d_in, const int* in_sizes, int n_in,
                              void* d_out, int out_size, void* d_ws, size_t ws_size,
                              hipStream_t stream) {
  const float* x    = (const float*)d_in[0];
  const float* gw   = (const float*)d_in[1];
  const float* gb   = (const float*)d_in[2];
  const float* qkvw = (const float*)d_in[3];
  const float* qkvb = (const float*)d_in[4];
  const float* outw = (const float*)d_in[5];
  const float* outb = (const float*)d_in[6];
  int B = in_sizes[0] / (CCH * NTOK);   // 4

  char* ws = (char*)d_ws;
  size_t off = 0;
  f16* H      = (f16*)(ws + off);   off += (size_t)B * CCH * NTOK * 2;   // 64 MiB
  f16* Ht     = (f16*)(ws + off);   off += (size_t)B * NTOK * CCH * 2;   // 64 MiB
  float* G    = (float*)(ws + off); off += (size_t)B * CCH * CCH * 4;    // 4 MiB
  f16* G16    = (f16*)(ws + off);   off += (size_t)B * CCH * CCH * 2;    // 2 MiB
  f16* T1h    = (f16*)(ws + off);   off += (size_t)B * CCH * CCH * 2;    // 2 MiB
  f16* Rt16   = (f16*)(ws + off);   off += (size_t)B * CCH * CCH * 2;    // 2 MiB
  f16* M16    = (f16*)(ws + off);   off += (size_t)B * CCH * CCH * 2;    // 2 MiB
  f16* Wqkv16 = (f16*)(ws + off);   off += (size_t)3 * CCH * CCH * 2;    // 1.5 MiB
  f16* Ow16   = (f16*)(ws + off);   off += (size_t)CCH * CCH * 2;        // 0.5 MiB
  f16* Wvt16  = (f16*)(ws + off);   off += (size_t)CCH * CCH * 2;        // 0.5 MiB
  float* pbv  = (float*)(ws + off); off += (size_t)B * CCH * 4;
  float* cvec = (float*)(ws + off); off += (size_t)B * CCH * 4;
  // zero-init region: stats, svec, bar (contiguous -> single memset)
  float* stats = (float*)(ws + off); off += (size_t)B * 8 * 2 * 4;
  float* svec  = (float*)(ws + off); off += (size_t)B * CCH * 4;
  int* bar     = (int*)(ws + off);   off += 8 * 4;
  size_t zbytes = (size_t)(B * 8 * 2 + B * CCH + 8) * 4;

  hipMemsetAsync(G, 0, (size_t)B * CCH * CCH * 4, stream);
  hipMemsetAsync(stats, 0, zbytes, stream);

  k_prep<<<dim3(2112), 256, 0, stream>>>(x, stats, qkvw, Wqkv16, outw, Ow16, Wvt16);
  k_gnorm<<<dim3(64, 8, B), 256, 0, stream>>>(x, gw, gb, stats, H, Ht, svec);
  k_syrk<<<dim3(10, SPLITS, B), 256, 0, stream>>>(H, G);
  k_mid<<<dim3(64), 256, 0, stream>>>(G, G16, Wqkv16, T1h, qkvw, qkvb, svec,
                                      Wvt16, Rt16, pbv, Ow16, M16,
                                      outw, outb, cvec, bar, B);
  k_out<<<dim3(128, 4, B), 256, 0, stream>>>(M16, Ht, x, cvec, (float*)d_out);
}

// Round 18
// 299.745 us; speedup vs baseline: 1.0767x; 1.0767x over previous
//
#include <hip/hip_runtime.h>
#include <hip/hip_fp16.h>

// AttentionBlock3D: channel attention. B=4, C=512, N=T*H*W=16384, 8 heads, d=64.
// Algebraic reduction: result = x + M*H + c, with
//   G = H H^T (per batch, SYMMETRIC -> upper tiles + mirror),
//   logits = scale*(Wq G Wk^T + rank-1), P = softmax per head,
//   M = out_w * blockdiag(P) * Wv, c = out_w * blockdiag(P) * bv + out_b.
//
// MFMA geometry LOCKED (R9): BK=64, 128B rows, XOR-swizzle slot^(row&7) (0 bank
//   conflicts), single 32KB LDS buffer, 2 barriers/K-step, lb(256,2).
//   k_out plateau 84-85us over 7 variants -> closed.
// R13: fp16 MFMA GEMMs w/ G16 = fp16(G-16384*I) + exact fp32 rank-shift restore.
// R15: fused k_attn (logits MFMA + softmax + PV MFMA). 359 -> 303us.
// R17 LESSON: software-barrier mega-fusion of the small middle chain REGRESSED
//   (k_mid 93us @ 2.7% occupancy vs ~74us as separate graph-replayed launches)
//   -> small launches beat barrier-fusion when phase grids are <=64 blocks.
// R18: revert to separate middle kernels (R16-identical bodies); keep k_prep
//   (independent-work concatenation: stats + casts + Wv-transpose, 2112 blocks).

#define CCH 512
#define NTOK 16384
#define NHEAD 8

typedef _Float16 f16;
typedef _Float16 f16x8 __attribute__((ext_vector_type(8)));
typedef float f32x4 __attribute__((ext_vector_type(4)));

__device__ __forceinline__ void g2l16(const void* g, void* l) {
  __builtin_amdgcn_global_load_lds((const __attribute__((address_space(1))) void*)g,
                                   (__attribute__((address_space(3))) void*)l,
                                   16, 0, 0);
}

// ---------------- K1: prep = GN stats + fp16 casts + Wv transpose (one launch) ----
__global__ __launch_bounds__(256) void k_prep(const float* __restrict__ x,
                                              float* __restrict__ stats,
                                              const float* __restrict__ qkvw,
                                              f16* __restrict__ Wqkv16,
                                              const float* __restrict__ outw,
                                              f16* __restrict__ Ow16,
                                              f16* __restrict__ Wvt16) {
  __shared__ __align__(16) char smp[9216];
  int bid = blockIdx.x;
  int t = threadIdx.x;
  if (bid < 1024) {                      // ---- GN stats ----
    int chunk = bid & 31, bg = bid >> 5;
    const float4* p = (const float4*)(x + (size_t)bg * (64ull * NTOK)) + (size_t)chunk * 8192;
    float s = 0.f, q = 0.f;
    for (int i = t; i < 8192; i += 256) {
      float4 v = p[i];
      s += v.x + v.y + v.z + v.w;
      q += v.x * v.x + v.y * v.y + v.z * v.z + v.w * v.w;
    }
    for (int off = 32; off; off >>= 1) { s += __shfl_down(s, off); q += __shfl_down(q, off); }
    float* ls = (float*)smp; float* lq = ls + 4;
    int wid = t >> 6, lane = t & 63;
    if (lane == 0) { ls[wid] = s; lq[wid] = q; }
    __syncthreads();
    if (t == 0) {
      atomicAdd(&stats[bg * 2 + 0], ls[0] + ls[1] + ls[2] + ls[3]);
      atomicAdd(&stats[bg * 2 + 1], lq[0] + lq[1] + lq[2] + lq[3]);
    }
  } else if (bid < 2048) {               // ---- fp32->fp16 casts ----
    bool isB = bid >= 1792;
    int i = (isB ? (bid - 1792) : (bid - 1024)) * 256 + t;
    const float* src = isB ? outw : qkvw;
    f16* dst = isB ? Ow16 : Wqkv16;
    float4 v = *(const float4*)&src[i * 4];
    f16 h[4] __attribute__((aligned(8)));
    h[0] = (f16)v.x; h[1] = (f16)v.y; h[2] = (f16)v.z; h[3] = (f16)v.w;
    *(uint2*)&dst[i * 4] = *(const uint2*)h;
  } else {                               // ---- Wv transpose-cast ----
    int j = bid - 2048;
    int et = j >> 3, ct = j & 7;
    f16 (*tl)[72] = (f16(*)[72])smp;
    int r = t >> 2, cq = (t & 3) * 16;
    const float* src = &qkvw[(size_t)(1024 + et * 64 + r) * CCH + ct * 64 + cq];
#pragma unroll
    for (int k = 0; k < 4; ++k) {
      float4 v = *(const float4*)(src + k * 4);
      tl[r][cq + k * 4 + 0] = (f16)v.x; tl[r][cq + k * 4 + 1] = (f16)v.y;
      tl[r][cq + k * 4 + 2] = (f16)v.z; tl[r][cq + k * 4 + 3] = (f16)v.w;
    }
    __syncthreads();
    f16 hv[16] __attribute__((aligned(16)));
#pragma unroll
    for (int jj = 0; jj < 16; ++jj) hv[jj] = tl[cq + jj][r];
    f16* dst = &Wvt16[(size_t)(ct * 64 + r) * CCH + et * 64 + cq];
    *(uint4*)&dst[0] = ((const uint4*)hv)[0];
    *(uint4*)&dst[8] = ((const uint4*)hv)[1];
  }
}

// ---------------- K2: normalize -> H (fp16 [b][c][n]), Ht (fp16 [b][n][c]), svec ----
__global__ __launch_bounds__(256) void k_gnorm(const float* __restrict__ x,
                                               const float* __restrict__ gw,
                                               const float* __restrict__ gb,
                                               const float* __restrict__ stats,
                                               f16* __restrict__ H, f16* __restrict__ Ht,
                                               float* __restrict__ svec) {
  int nc = blockIdx.x;   // n chunk (256 tokens)
  int cg = blockIdx.y;   // channel group (64 ch) == GN group
  int b = blockIdx.z;
  int t = threadIdx.x;
  __shared__ f16 T2[64][260];
  __shared__ float svp[4][64];
  float sum = stats[(b * 8 + cg) * 2], sq = stats[(b * 8 + cg) * 2 + 1];
  const float inv = 1.f / (64.f * (float)NTOK);
  float mean = sum * inv;
  float var = fmaxf(sq * inv - mean * mean, 0.f);
  float rsig = rsqrtf(var + 1e-5f);
  int c0 = cg * 64, n0 = nc * 256;
  int tq = t & 63, rr0 = t >> 6;
#pragma unroll
  for (int it = 0; it < 16; ++it) {
    int r = it * 4 + rr0;
    int c = c0 + r;
    float a = gw[c] * rsig;
    float bb = gb[c] - mean * a;
    size_t idx = ((size_t)(b * CCH + c)) * NTOK + n0 + tq * 4;
    float4 xv = *(const float4*)&x[idx];
    f16 hh[4] __attribute__((aligned(8)));
    hh[0] = (f16)(xv.x * a + bb);
    hh[1] = (f16)(xv.y * a + bb);
    hh[2] = (f16)(xv.z * a + bb);
    hh[3] = (f16)(xv.w * a + bb);
    *(uint2*)&H[idx] = *(const uint2*)hh;
    *(uint2*)&T2[r][tq * 4] = *(const uint2*)hh;
  }
  __syncthreads();
  {
    int c = t & 63, q = t >> 6;
    float acc = 0.f;
#pragma unroll
    for (int j = 0; j < 64; ++j) acc += (float)T2[c][q * 64 + j];
    svp[q][c] = acc;
  }
  __syncthreads();
  if (t < 64) {
    atomicAdd(&svec[b * CCH + c0 + t],
              svp[0][t] + svp[1][t] + svp[2][t] + svp[3][t]);
  }
  int s8 = t & 7, nl = t >> 3;
#pragma unroll
  for (int it = 0; it < 8; ++it) {
    int n = it * 32 + nl;
    f16 g[8] __attribute__((aligned(16)));
#pragma unroll
    for (int j = 0; j < 8; ++j) g[j] = T2[s8 * 8 + j][n];
    *(uint4*)&Ht[((size_t)b * NTOK + n0 + n) * CCH + c0 + s8 * 8] = *(const uint4*)g;
  }
}

// ---------------- K3: G = H H^T, upper tiles, split-K=16, BK=64 single-buf (32KB) ----
#define SPLITS 16
__global__ __launch_bounds__(256, 2) void k_syrk(const f16* __restrict__ H,
                                                 float* __restrict__ G) {
  const int TI[10] = {0, 0, 0, 0, 1, 1, 1, 2, 2, 3};
  const int TJ[10] = {0, 1, 2, 3, 1, 2, 3, 2, 3, 3};
  int tile = blockIdx.x;
  int split = blockIdx.y;
  int b = blockIdx.z;
  int ii = TI[tile], jj = TJ[tile];
  int m0 = ii * 128, n0 = jj * 128;
  int t = threadIdx.x, lane = t & 63, wid = t >> 6;
  int wr = wid >> 1, wc = wid & 1;
  __shared__ __align__(16) f16 sA[128 * 64];
  __shared__ __align__(16) f16 sB[128 * 64];
  const f16* Hb = H + (size_t)b * CCH * NTOK;
  int k0 = split * (NTOK / SPLITS);
  f32x4 acc[4][4] = {};
  int ldsrow = wid * 8 + (lane >> 3);
  int slot = lane & 7;
  int lr = lane & 15, lk = lane >> 4;

  const int NS = (NTOK / SPLITS) / 64;
  for (int ks = 0; ks < NS; ++ks) {
    int kk0 = k0 + ks * 64;
    __syncthreads();
#pragma unroll
    for (int i = 0; i < 4; ++i) {
      int row = ldsrow + i * 32;
      int cA = ((slot ^ (row & 7)) * 8);
      g2l16(Hb + (size_t)(m0 + row) * NTOK + kk0 + cA, &sA[i * 2048 + wid * 512]);
      g2l16(Hb + (size_t)(n0 + row) * NTOK + kk0 + cA, &sB[i * 2048 + wid * 512]);
    }
    asm volatile("s_waitcnt vmcnt(0)" ::: "memory");
    __syncthreads();
#pragma unroll
    for (int kk = 0; kk < 2; ++kk) {
      f16x8 af[4], bf[4];
#pragma unroll
      for (int mi = 0; mi < 4; ++mi) {
        int row = wr * 64 + mi * 16 + lr;
        int ks8 = (kk * 4 + lk) ^ (row & 7);
        af[mi] = *(const f16x8*)&sA[row * 64 + ks8 * 8];
      }
#pragma unroll
      for (int ni = 0; ni < 4; ++ni) {
        int row = wc * 64 + ni * 16 + lr;
        int ks8 = (kk * 4 + lk) ^ (row & 7);
        bf[ni] = *(const f16x8*)&sB[row * 64 + ks8 * 8];
      }
#pragma unroll
      for (int mi = 0; mi < 4; ++mi)
#pragma unroll
        for (int ni = 0; ni < 4; ++ni)
          acc[mi][ni] = __builtin_amdgcn_mfma_f32_16x16x32_f16(af[mi], bf[ni], acc[mi][ni], 0, 0, 0);
    }
  }

  float* Gb = G + (size_t)b * CCH * CCH;
#pragma unroll
  for (int mi = 0; mi < 4; ++mi)
#pragma unroll
    for (int j = 0; j < 4; ++j) {
      int rr2 = m0 + wr * 64 + mi * 16 + lk * 4 + j;
#pragma unroll
      for (int ni = 0; ni < 4; ++ni) {
        int cc = n0 + wc * 64 + ni * 16 + lr;
        atomicAdd(&Gb[(size_t)rr2 * CCH + cc], acc[mi][ni][j]);
      }
    }
}

// ---------------- K3b: mirror upper off-diag tiles + cast full G -> G16 ------------
__global__ __launch_bounds__(256) void k_symm(float* __restrict__ G,
                                              f16* __restrict__ G16) {
  const int TI6[6] = {0, 0, 0, 1, 1, 2};
  const int TJ6[6] = {1, 2, 3, 2, 3, 3};
  int bx = blockIdx.x;
  int b = blockIdx.y;
  float* Gb = G + (size_t)b * CCH * CCH;
  f16* Gh = G16 + (size_t)b * CCH * CCH;
  __shared__ float s[64][65];
  int t = threadIdx.x;
  int r = t >> 2, cg = (t & 3) * 16;
  int ib, jb;
  bool mirror = bx < 24;
  if (mirror) {
    int t6 = bx >> 2, sub = bx & 3;
    ib = TI6[t6] * 2 + (sub >> 1); jb = TJ6[t6] * 2 + (sub & 1);
  } else {
    int idx = bx - 24; int dt = idx >> 2, sub = idx & 3;
    ib = dt * 2 + (sub >> 1); jb = dt * 2 + (sub & 1);
  }
  int grow = ib * 64 + r, gcol0 = jb * 64 + cg;
  const float* src = &Gb[(size_t)grow * CCH + gcol0];
  f16 hv[16] __attribute__((aligned(16)));
#pragma unroll
  for (int k = 0; k < 4; ++k) {
    float4 v = *(const float4*)(src + k * 4);
    if (mirror) {
      s[r][cg + k * 4 + 0] = v.x; s[r][cg + k * 4 + 1] = v.y;
      s[r][cg + k * 4 + 2] = v.z; s[r][cg + k * 4 + 3] = v.w;
    }
    hv[k * 4 + 0] = (f16)(v.x - ((grow == gcol0 + k * 4 + 0) ? 16384.f : 0.f));
    hv[k * 4 + 1] = (f16)(v.y - ((grow == gcol0 + k * 4 + 1) ? 16384.f : 0.f));
    hv[k * 4 + 2] = (f16)(v.z - ((grow == gcol0 + k * 4 + 2) ? 16384.f : 0.f));
    hv[k * 4 + 3] = (f16)(v.w - ((grow == gcol0 + k * 4 + 3) ? 16384.f : 0.f));
  }
  f16* d16 = &Gh[(size_t)grow * CCH + gcol0];
  *(uint4*)&d16[0] = ((const uint4*)hv)[0];
  *(uint4*)&d16[8] = ((const uint4*)hv)[1];
  if (mirror) {
    __syncthreads();
    float* dst = &Gb[(size_t)(jb * 64 + r) * CCH + ib * 64 + cg];
    f16 hw[16] __attribute__((aligned(16)));
#pragma unroll
    for (int k = 0; k < 4; ++k) {
      float4 v;
      v.x = s[cg + k * 4 + 0][r]; v.y = s[cg + k * 4 + 1][r];
      v.z = s[cg + k * 4 + 2][r]; v.w = s[cg + k * 4 + 3][r];
      *(float4*)(dst + k * 4) = v;
      hw[k * 4 + 0] = (f16)v.x; hw[k * 4 + 1] = (f16)v.y;
      hw[k * 4 + 2] = (f16)v.z; hw[k * 4 + 3] = (f16)v.w;
    }
    f16* m16 = &Gh[(size_t)(jb * 64 + r) * CCH + ib * 64 + cg];
    *(uint4*)&m16[0] = ((const uint4*)hw)[0];
    *(uint4*)&m16[8] = ((const uint4*)hw)[1];
  }
}

// ---------------- K4: fp16 MFMA 512^3 GEMM: C[b] = A16 @ Bt16[b]^T ----------------
template <bool CORR>
__global__ __launch_bounds__(256, 2) void k_hgemm512(const f16* __restrict__ A16,
                                                     const f16* __restrict__ Bt16,
                                                     f16* __restrict__ Cv,
                                                     const float* __restrict__ corr) {
  int n0 = blockIdx.x * 128, m0 = blockIdx.y * 128, b = blockIdx.z;
  int t = threadIdx.x, lane = t & 63, wid = t >> 6;
  int wr = wid >> 1, wc = wid & 1;
  __shared__ __align__(16) f16 sA[128 * 64];
  __shared__ __align__(16) f16 sB[128 * 64];
  const f16* Bp = Bt16 + (size_t)b * CCH * CCH;
  f32x4 acc[4][4] = {};
  int ldsrow = wid * 8 + (lane >> 3);
  int slot = lane & 7;
  int lr = lane & 15, lk = lane >> 4;
  for (int ks = 0; ks < 8; ++ks) {
    int kk0 = ks * 64;
    __syncthreads();
#pragma unroll
    for (int i = 0; i < 4; ++i) {
      int row = ldsrow + i * 32;
      int cA = ((slot ^ (row & 7)) * 8);
      g2l16(A16 + (size_t)(m0 + row) * CCH + kk0 + cA, &sA[i * 2048 + wid * 512]);
      g2l16(Bp + (size_t)(n0 + row) * CCH + kk0 + cA, &sB[i * 2048 + wid * 512]);
    }
    asm volatile("s_waitcnt vmcnt(0)" ::: "memory");
    __syncthreads();
#pragma unroll
    for (int kk = 0; kk < 2; ++kk) {
      f16x8 af[4], bf[4];
#pragma unroll
      for (int mi = 0; mi < 4; ++mi) {
        int row = wr * 64 + mi * 16 + lr;
        int ks8 = (kk * 4 + lk) ^ (row & 7);
        af[mi] = *(const f16x8*)&sA[row * 64 + ks8 * 8];
      }
#pragma unroll
      for (int ni = 0; ni < 4; ++ni) {
        int row = wc * 64 + ni * 16 + lr;
        int ks8 = (kk * 4 + lk) ^ (row & 7);
        bf[ni] = *(const f16x8*)&sB[row * 64 + ks8 * 8];
      }
#pragma unroll
      for (int mi = 0; mi < 4; ++mi)
#pragma unroll
        for (int ni = 0; ni < 4; ++ni)
          acc[mi][ni] = __builtin_amdgcn_mfma_f32_16x16x32_f16(af[mi], bf[ni], acc[mi][ni], 0, 0, 0);
    }
  }
#pragma unroll
  for (int mi = 0; mi < 4; ++mi)
#pragma unroll
    for (int j = 0; j < 4; ++j) {
      int o = m0 + wr * 64 + mi * 16 + lk * 4 + j;
#pragma unroll
      for (int ni = 0; ni < 4; ++ni) {
        int n = n0 + wc * 64 + ni * 16 + lr;
        float v = acc[mi][ni][j];
        if constexpr (CORR) v += 16384.f * corr[(size_t)o * CCH + n];
        Cv[(size_t)b * CCH * CCH + (size_t)o * CCH + n] = (f16)v;
      }
    }
}

// ---------------- K5: fused per-(b,h) attention ----------------
__global__ __launch_bounds__(256) void k_attn(const f16* __restrict__ T1h,
                                              const f16* __restrict__ Wqkv16,
                                              const f16* __restrict__ Wvt16,
                                              const float* __restrict__ qkvw,
                                              const float* __restrict__ qkvb,
                                              const float* __restrict__ svec,
                                              f16* __restrict__ Rt16,
                                              float* __restrict__ pbv) {
  int h = blockIdx.x, b = blockIdx.y;
  int h64 = h * 64;
  int t = threadIdx.x, lane = t & 63, wid = t >> 6;
  int lr = lane & 15, lk = lane >> 4;
  __shared__ float ss[512];
  __shared__ float suq[64], suk[64], sbq[64], sbk[64], sbv[64];
  __shared__ float Lsm[64][68];
  __shared__ f16 Psm[64][72];

  for (int i = t; i < 512; i += 256) ss[i] = svec[b * CCH + i];
  if (t < 64) {
    sbq[t] = qkvb[h64 + t];
    sbk[t] = qkvb[512 + h64 + t];
    sbv[t] = qkvb[1024 + h64 + t];
  }
  __syncthreads();
  if (t < 128) {
    int o = t & 63; bool isk = t >= 64;
    const float* wr_ = qkvw + (size_t)((isk ? 512 : 0) + h64 + o) * CCH;
    float a = 0.f;
#pragma unroll
    for (int i = 0; i < 128; ++i) {
      float4 w = *(const float4*)&wr_[i * 4];
      a += w.x * ss[i * 4] + w.y * ss[i * 4 + 1] + w.z * ss[i * 4 + 2] + w.w * ss[i * 4 + 3];
    }
    (isk ? suk : suq)[o] = a;
  }
  int wr = wid >> 1, wc = wid & 1;
  f32x4 lacc[2][2] = {};
  const f16* Ab = T1h + (size_t)b * CCH * CCH;
  const f16* Bb = Wqkv16 + (size_t)(512 + h64) * CCH;
  for (int ks = 0; ks < 16; ++ks) {
    int kq = ks * 32 + lk * 8;
    f16x8 af[2], bf[2];
#pragma unroll
    for (int mi = 0; mi < 2; ++mi)
      af[mi] = *(const f16x8*)&Ab[(size_t)(h64 + wr * 32 + mi * 16 + lr) * CCH + kq];
#pragma unroll
    for (int ni = 0; ni < 2; ++ni)
      bf[ni] = *(const f16x8*)&Bb[(size_t)(wc * 32 + ni * 16 + lr) * CCH + kq];
#pragma unroll
    for (int mi = 0; mi < 2; ++mi)
#pragma unroll
      for (int ni = 0; ni < 2; ++ni)
        lacc[mi][ni] = __builtin_amdgcn_mfma_f32_16x16x32_f16(af[mi], bf[ni], lacc[mi][ni], 0, 0, 0);
  }
  __syncthreads();
#pragma unroll
  for (int mi = 0; mi < 2; ++mi)
#pragma unroll
    for (int ni = 0; ni < 2; ++ni)
#pragma unroll
      for (int j = 0; j < 4; ++j) {
        int d = wr * 32 + mi * 16 + lk * 4 + j;
        int e = wc * 32 + ni * 16 + lr;
        Lsm[d][e] = (lacc[mi][ni][j] + suq[d] * sbk[e] + sbq[d] * suk[e]
                     + 16384.f * sbq[d] * sbk[e]) * 0.125f;
      }
  __syncthreads();
  if (t < 64) {
    float m = -1e30f;
#pragma unroll
    for (int e = 0; e < 64; ++e) m = fmaxf(m, Lsm[t][e]);
    float p[64];
    float sum = 0.f;
#pragma unroll
    for (int e = 0; e < 64; ++e) { p[e] = expf(Lsm[t][e] - m); sum += p[e]; }
    float r = 1.f / sum, pb = 0.f;
#pragma unroll
    for (int e = 0; e < 64; ++e) {
      float pv = p[e] * r;
      Psm[t][e] = (f16)pv;
      pb += pv * sbv[e];
    }
    pbv[b * CCH + h64 + t] = pb;
  }
  __syncthreads();
  f32x4 acc[4][8] = {};
  int c0w = wid * 128;
#pragma unroll
  for (int kk = 0; kk < 2; ++kk) {
    int e0 = kk * 32 + lk * 8;
    f16x8 pa[4], wb[8];
#pragma unroll
    for (int mi = 0; mi < 4; ++mi)
      pa[mi] = *(const f16x8*)&Psm[mi * 16 + lr][e0];
#pragma unroll
    for (int ni = 0; ni < 8; ++ni)
      wb[ni] = *(const f16x8*)&Wvt16[(size_t)(c0w + ni * 16 + lr) * CCH + h64 + e0];
#pragma unroll
    for (int mi = 0; mi < 4; ++mi)
#pragma unroll
      for (int ni = 0; ni < 8; ++ni)
        acc[mi][ni] = __builtin_amdgcn_mfma_f32_16x16x32_f16(pa[mi], wb[ni], acc[mi][ni], 0, 0, 0);
  }
#pragma unroll
  for (int mi = 0; mi < 4; ++mi)
#pragma unroll
    for (int ni = 0; ni < 8; ++ni) {
      int d0 = mi * 16 + lk * 4;
      int c = c0w + ni * 16 + lr;
      f16 hv[4] __attribute__((aligned(8)));
#pragma unroll
      for (int j = 0; j < 4; ++j) hv[j] = (f16)acc[mi][ni][j];
      *(uint2*)&Rt16[((size_t)b * CCH + c) * CCH + h64 + d0] = *(const uint2*)hv;
    }
}

// ---------------- K4d: cvec = out_w @ pbv + out_b (4 lanes/output) ----------------
__global__ __launch_bounds__(256) void k_cvec(const float* __restrict__ outw,
                                              const float* __restrict__ outb,
                                              const float* __restrict__ pbv,
                                              float* __restrict__ cvec) {
  int o = blockIdx.x * 64 + (threadIdx.x >> 2);   // grid.x = 8
  int l = threadIdx.x & 3;
  int b = blockIdx.y;
  __shared__ float sp[512];
  for (int i = threadIdx.x; i < 512; i += 256) sp[i] = pbv[b * CCH + i];
  __syncthreads();
  const float* wr_ = outw + (size_t)o * CCH + l * 128;
  const float* spp = sp + l * 128;
  float a = 0.f;
#pragma unroll
  for (int i = 0; i < 32; ++i) {
    float4 w = *(const float4*)&wr_[i * 4];
    a += w.x * spp[i * 4] + w.y * spp[i * 4 + 1] + w.z * spp[i * 4 + 2] + w.w * spp[i * 4 + 3];
  }
  a += __shfl_down(a, 2);
  a += __shfl_down(a, 1);
  if (l == 0) cvec[b * CCH + o] = a + outb[o];
}

// ---------------- K6: out = x + M16 @ H + cvec (fp16 MFMA, transposed fragment) ----
__global__ __launch_bounds__(256, 2) void k_out(const f16* __restrict__ M16,
                                                const f16* __restrict__ Ht,
                                                const float* __restrict__ x,
                                                const float* __restrict__ cvec,
                                                float* __restrict__ out) {
  int nt = blockIdx.x;   // 128 n-tiles
  int mt = blockIdx.y;   // 4 o-tiles
  int b = blockIdx.z;
  int m0 = mt * 128, n0 = nt * 128;
  int t = threadIdx.x, lane = t & 63, wid = t >> 6;
  int wr = wid >> 1, wc = wid & 1;
  __shared__ __align__(16) f16 sA[128 * 64];
  __shared__ __align__(16) f16 sB[128 * 64];
  const f16* A = M16 + (size_t)b * CCH * CCH;
  const f16* Bp = Ht + (size_t)b * NTOK * CCH;
  f32x4 acc[4][4] = {};
  int ldsrow = wid * 8 + (lane >> 3);
  int slot = lane & 7;
  int lr = lane & 15, lk = lane >> 4;
  for (int ks = 0; ks < 8; ++ks) {
    int kk0 = ks * 64;
    __syncthreads();
#pragma unroll
    for (int i = 0; i < 4; ++i) {
      int row = ldsrow + i * 32;
      int cA = ((slot ^ (row & 7)) * 8);
      g2l16(A + (size_t)(m0 + row) * CCH + kk0 + cA, &sA[i * 2048 + wid * 512]);
      g2l16(Bp + (size_t)(n0 + row) * CCH + kk0 + cA, &sB[i * 2048 + wid * 512]);
    }
    asm volatile("s_waitcnt vmcnt(0)" ::: "memory");
    __syncthreads();
#pragma unroll
    for (int kk = 0; kk < 2; ++kk) {
      f16x8 af[4], bf[4];
#pragma unroll
      for (int mi = 0; mi < 4; ++mi) {
        int row = wr * 64 + mi * 16 + lr;
        int ks8 = (kk * 4 + lk) ^ (row & 7);
        af[mi] = *(const f16x8*)&sA[row * 64 + ks8 * 8];
      }
#pragma unroll
      for (int ni = 0; ni < 4; ++ni) {
        int row = wc * 64 + ni * 16 + lr;
        int ks8 = (kk * 4 + lk) ^ (row & 7);
        bf[ni] = *(const f16x8*)&sB[row * 64 + ks8 * 8];
      }
#pragma unroll
      for (int mi = 0; mi < 4; ++mi)
#pragma unroll
        for (int ni = 0; ni < 4; ++ni)   // swapped: D[n][o] fragment
          acc[mi][ni] = __builtin_amdgcn_mfma_f32_16x16x32_f16(bf[ni], af[mi], acc[mi][ni], 0, 0, 0);
    }
  }

  const float* xb = x + ((size_t)b * CCH) * NTOK;
  float* ob = out + ((size_t)b * CCH) * NTOK;
#pragma unroll
  for (int mi = 0; mi < 4; ++mi) {
    int o = m0 + wr * 64 + mi * 16 + lr;
    float cv = cvec[b * CCH + o];
    size_t rowoff = (size_t)o * NTOK;
#pragma unroll
    for (int ni = 0; ni < 4; ++ni) {
      int n = n0 + wc * 64 + ni * 16 + lk * 4;
      float4 xv = *(const float4*)&xb[rowoff + n];
      float4 ov;
      ov.x = xv.x + acc[mi][ni][0] + cv;
      ov.y = xv.y + acc[mi][ni][1] + cv;
      ov.z = xv.z + acc[mi][ni][2] + cv;
      ov.w = xv.w + acc[mi][ni][3] + cv;
      *(float4*)&ob[rowoff + n] = ov;
    }
  }
}

extern "C" void kernel_launch(void* const* d_in, const int* in_sizes, int n_in,
                              void* d_out, int out_size, void* d_ws, size_t ws_size,
                              hipStream_t stream) {
  const float* x    = (const float*)d_in[0];
  const float* gw   = (const float*)d_in[1];
  const float* gb   = (const float*)d_in[2];
  const float* qkvw = (const float*)d_in[3];
  const float* qkvb = (const float*)d_in[4];
  const float* outw = (const float*)d_in[5];
  const float* outb = (const float*)d_in[6];
  int B = in_sizes[0] / (CCH * NTOK);   // 4

  char* ws = (char*)d_ws;
  size_t off = 0;
  f16* H      = (f16*)(ws + off);   off += (size_t)B * CCH * NTOK * 2;   // 64 MiB
  f16* Ht     = (f16*)(ws + off);   off += (size_t)B * NTOK * CCH * 2;   // 64 MiB
  float* G    = (float*)(ws + off); off += (size_t)B * CCH * CCH * 4;    // 4 MiB
  f16* G16    = (f16*)(ws + off);   off += (size_t)B * CCH * CCH * 2;    // 2 MiB
  f16* T1h    = (f16*)(ws + off);   off += (size_t)B * CCH * CCH * 2;    // 2 MiB
  f16* Rt16   = (f16*)(ws + off);   off += (size_t)B * CCH * CCH * 2;    // 2 MiB
  f16* M16    = (f16*)(ws + off);   off += (size_t)B * CCH * CCH * 2;    // 2 MiB
  f16* Wqkv16 = (f16*)(ws + off);   off += (size_t)3 * CCH * CCH * 2;    // 1.5 MiB
  f16* Ow16   = (f16*)(ws + off);   off += (size_t)CCH * CCH * 2;        // 0.5 MiB
  f16* Wvt16  = (f16*)(ws + off);   off += (size_t)CCH * CCH * 2;        // 0.5 MiB
  float* pbv  = (float*)(ws + off); off += (size_t)B * CCH * 4;
  float* cvec = (float*)(ws + off); off += (size_t)B * CCH * 4;
  // zero-init region: stats, svec (contiguous -> single memset)
  float* stats = (float*)(ws + off); off += (size_t)B * 8 * 2 * 4;
  float* svec  = (float*)(ws + off); off += (size_t)B * CCH * 4;
  size_t zbytes = (size_t)(B * 8 * 2 + B * CCH) * 4;

  hipMemsetAsync(G, 0, (size_t)B * CCH * CCH * 4, stream);
  hipMemsetAsync(stats, 0, zbytes, stream);

  k_prep<<<dim3(2112), 256, 0, stream>>>(x, stats, qkvw, Wqkv16, outw, Ow16, Wvt16);
  k_gnorm<<<dim3(64, 8, B), 256, 0, stream>>>(x, gw, gb, stats, H, Ht, svec);
  k_syrk<<<dim3(10, SPLITS, B), 256, 0, stream>>>(H, G);
  k_symm<<<dim3(40, B), 256, 0, stream>>>(G, G16);
  k_hgemm512<true><<<dim3(4, 4, B), 256, 0, stream>>>(Wqkv16, G16, T1h, qkvw);
  k_attn<<<dim3(NHEAD, B), 256, 0, stream>>>(T1h, Wqkv16, Wvt16, qkvw, qkvb, svec,
                                             Rt16, pbv);
  k_hgemm512<false><<<dim3(4, 4, B), 256, 0, stream>>>(Ow16, Rt16, M16, nullptr);
  k_cvec<<<dim3(8, B), 256, 0, stream>>>(outw, outb, pbv, cvec);
  k_out<<<dim3(128, 4, B), 256, 0, stream>>>(M16, Ht, x, cvec, (float*)d_out);
}

// Round 19
// 277.214 us; speedup vs baseline: 1.1642x; 1.0813x over previous
//
#include <hip/hip_runtime.h>
#include <hip/hip_fp16.h>

// AttentionBlock3D: channel attention. B=4, C=512, N=T*H*W=16384, 8 heads, d=64.
// R19 formulation: GroupNorm folded algebraically (H = D_a x + b 1^T never
// materialized):
//   X = x16 x16^T (syrk on fp16-cast x), sx = x 1,
//   G_H = D_a X D_a + asx b^T + b asx^T + N b b^T  (applied in k_symm2 cast),
//   logits chain unchanged via G16 = fp16(G_H - 16384 I) + exact fp32 restore,
//   M H = (M D_a) x + (M b) 1^T: k_out uses Ma16 (col-scaled) x xt16; M b folds
//   into cvec via bv += Wv b (y-vector) inside k_attn's pbv.
// MFMA geometry LOCKED (R9): BK=64, XOR-swizzle slot^(row&7), 0 bank conflicts,
//   single 32KB LDS, 2 barriers/K-step, lb(256,2). k_out plateau 84-85us (closed).
// R17 LESSON: software-barrier mega-fusion regressed (2.7% occupancy);
//   graph-replayed small launches win for <=64-block phases.

#define CCH 512
#define NTOK 16384
#define NHEAD 8

typedef _Float16 f16;
typedef _Float16 f16x8 __attribute__((ext_vector_type(8)));
typedef float f32x4 __attribute__((ext_vector_type(4)));

__device__ __forceinline__ void g2l16(const void* g, void* l) {
  __builtin_amdgcn_global_load_lds((const __attribute__((address_space(1))) void*)g,
                                   (__attribute__((address_space(3))) void*)l,
                                   16, 0, 0);
}

// ---------------- K1: one pass over x + weight casts ----------------
// blocks [0,2048): x-tile pass -> stats(atomic), x16, xt16, sx(atomic)
// [2048,2816): cast qkvw->Wqkv16; [2816,3072): cast outw->Ow16;
// [3072,3136): Wvt16[c][e] = fp16(qkvw[1024+e][c]).
__global__ __launch_bounds__(256) void k_prep2(const float* __restrict__ x,
                                               float* __restrict__ stats,
                                               float* __restrict__ sx,
                                               f16* __restrict__ x16,
                                               f16* __restrict__ xt16,
                                               const float* __restrict__ qkvw,
                                               f16* __restrict__ Wqkv16,
                                               const float* __restrict__ outw,
                                               f16* __restrict__ Ow16,
                                               f16* __restrict__ Wvt16) {
  __shared__ __align__(16) char smp[34816];
  int bid = blockIdx.x;
  int t = threadIdx.x;
  if (bid < 2048) {                      // ---- x pass ----
    f16 (*T2)[260] = (f16(*)[260])smp;            // 33280 B
    float (*svp)[64] = (float(*)[64])(smp + 33280); // 1024 B
    float* lsq = (float*)(smp + 34304);            // 8 floats
    int nc = bid & 63, cg = (bid >> 6) & 7, b = bid >> 9;
    int c0 = cg * 64, n0 = nc * 256;
    int tq = t & 63, rr0 = t >> 6;
    float s = 0.f, q = 0.f;
#pragma unroll
    for (int it = 0; it < 16; ++it) {
      int r = it * 4 + rr0;
      int c = c0 + r;
      size_t idx = ((size_t)(b * CCH + c)) * NTOK + n0 + tq * 4;
      float4 xv = *(const float4*)&x[idx];
      s += xv.x + xv.y + xv.z + xv.w;
      q += xv.x * xv.x + xv.y * xv.y + xv.z * xv.z + xv.w * xv.w;
      f16 hh[4] __attribute__((aligned(8)));
      hh[0] = (f16)xv.x; hh[1] = (f16)xv.y; hh[2] = (f16)xv.z; hh[3] = (f16)xv.w;
      *(uint2*)&x16[idx] = *(const uint2*)hh;
      *(uint2*)&T2[r][tq * 4] = *(const uint2*)hh;
    }
    for (int off = 32; off; off >>= 1) { s += __shfl_down(s, off); q += __shfl_down(q, off); }
    int wid = t >> 6, lane = t & 63;
    if (lane == 0) { lsq[wid] = s; lsq[4 + wid] = q; }
    __syncthreads();
    if (t == 0) {
      atomicAdd(&stats[(b * 8 + cg) * 2 + 0], lsq[0] + lsq[1] + lsq[2] + lsq[3]);
      atomicAdd(&stats[(b * 8 + cg) * 2 + 1], lsq[4] + lsq[5] + lsq[6] + lsq[7]);
    }
    {
      int c = t & 63, qd = t >> 6;
      float acc = 0.f;
#pragma unroll
      for (int j = 0; j < 64; ++j) acc += (float)T2[c][qd * 64 + j];
      svp[qd][c] = acc;
    }
    __syncthreads();
    if (t < 64) {
      atomicAdd(&sx[b * CCH + c0 + t],
                svp[0][t] + svp[1][t] + svp[2][t] + svp[3][t]);
    }
    int s8 = t & 7, nl = t >> 3;
#pragma unroll
    for (int it = 0; it < 8; ++it) {
      int n = it * 32 + nl;
      f16 g[8] __attribute__((aligned(16)));
#pragma unroll
      for (int j = 0; j < 8; ++j) g[j] = T2[s8 * 8 + j][n];
      *(uint4*)&xt16[((size_t)b * NTOK + n0 + n) * CCH + c0 + s8 * 8] = *(const uint4*)g;
    }
  } else if (bid < 3072) {               // ---- weight casts ----
    int bid2 = bid - 2048;
    bool isB = bid2 >= 768;
    int i = (isB ? (bid2 - 768) : bid2) * 256 + t;
    const float* src = isB ? outw : qkvw;
    f16* dst = isB ? Ow16 : Wqkv16;
    float4 v = *(const float4*)&src[i * 4];
    f16 h[4] __attribute__((aligned(8)));
    h[0] = (f16)v.x; h[1] = (f16)v.y; h[2] = (f16)v.z; h[3] = (f16)v.w;
    *(uint2*)&dst[i * 4] = *(const uint2*)h;
  } else {                               // ---- Wv transpose-cast ----
    int j = bid - 3072;
    int et = j >> 3, ct = j & 7;
    f16 (*tl)[72] = (f16(*)[72])smp;
    int r = t >> 2, cq = (t & 3) * 16;
    const float* src = &qkvw[(size_t)(1024 + et * 64 + r) * CCH + ct * 64 + cq];
#pragma unroll
    for (int k = 0; k < 4; ++k) {
      float4 v = *(const float4*)(src + k * 4);
      tl[r][cq + k * 4 + 0] = (f16)v.x; tl[r][cq + k * 4 + 1] = (f16)v.y;
      tl[r][cq + k * 4 + 2] = (f16)v.z; tl[r][cq + k * 4 + 3] = (f16)v.w;
    }
    __syncthreads();
    f16 hv[16] __attribute__((aligned(16)));
#pragma unroll
    for (int jj = 0; jj < 16; ++jj) hv[jj] = tl[cq + jj][r];
    f16* dst = &Wvt16[(size_t)(ct * 64 + r) * CCH + et * 64 + cq];
    *(uint4*)&dst[0] = ((const uint4*)hv)[0];
    *(uint4*)&dst[8] = ((const uint4*)hv)[1];
  }
}

// ---------------- K2: per-batch GN vectors + y = Wv @ b ----------------
// avec=a, bvec=b, asxv=a*sx, svecH=a*sx+N*b (== old svec), yvec=Wv@b.
__global__ __launch_bounds__(256) void k_ab(const float* __restrict__ stats,
                                            const float* __restrict__ gw,
                                            const float* __restrict__ gb,
                                            const float* __restrict__ sx,
                                            const float* __restrict__ qkvw,
                                            float* __restrict__ avec,
                                            float* __restrict__ bvec,
                                            float* __restrict__ asxv,
                                            float* __restrict__ svecH,
                                            float* __restrict__ yvec) {
  int ob = blockIdx.x, b = blockIdx.y;
  int t = threadIdx.x;
  __shared__ float smean[8], srsig[8], sb[512];
  if (t < 8) {
    const float inv = 1.f / (64.f * (float)NTOK);
    float sum = stats[(b * 8 + t) * 2], sq = stats[(b * 8 + t) * 2 + 1];
    float mean = sum * inv;
    float var = fmaxf(sq * inv - mean * mean, 0.f);
    smean[t] = mean; srsig[t] = rsqrtf(var + 1e-5f);
  }
  __syncthreads();
  for (int c = t; c < 512; c += 256) {
    int g = c >> 6;
    float a = gw[c] * srsig[g];
    sb[c] = gb[c] - smean[g] * a;
  }
  __syncthreads();
  if (t < 64) {
    int c = ob * 64 + t; int g = c >> 6;
    float a = gw[c] * srsig[g];
    float bb = sb[c];
    float sxc = sx[b * CCH + c];
    avec[b * CCH + c] = a;
    bvec[b * CCH + c] = bb;
    asxv[b * CCH + c] = a * sxc;
    svecH[b * CCH + c] = a * sxc + (float)NTOK * bb;
  }
  int e = ob * 64 + (t >> 2);
  int l = t & 3;
  const float* wr_ = qkvw + (size_t)(1024 + e) * CCH + l * 128;
  const float* sbb = sb + l * 128;
  float acc = 0.f;
#pragma unroll
  for (int i = 0; i < 32; ++i) {
    float4 w = *(const float4*)&wr_[i * 4];
    acc += w.x * sbb[i * 4] + w.y * sbb[i * 4 + 1] + w.z * sbb[i * 4 + 2] + w.w * sbb[i * 4 + 3];
  }
  acc += __shfl_down(acc, 2);
  acc += __shfl_down(acc, 1);
  if (l == 0) yvec[b * CCH + e] = acc;
}

// ---------------- K3: X = x16 x16^T, upper tiles, split-K=16, BK=64 (32KB) ----
#define SPLITS 16
__global__ __launch_bounds__(256, 2) void k_syrk(const f16* __restrict__ H,
                                                 float* __restrict__ G) {
  const int TI[10] = {0, 0, 0, 0, 1, 1, 1, 2, 2, 3};
  const int TJ[10] = {0, 1, 2, 3, 1, 2, 3, 2, 3, 3};
  int tile = blockIdx.x;
  int split = blockIdx.y;
  int b = blockIdx.z;
  int ii = TI[tile], jj = TJ[tile];
  int m0 = ii * 128, n0 = jj * 128;
  int t = threadIdx.x, lane = t & 63, wid = t >> 6;
  int wr = wid >> 1, wc = wid & 1;
  __shared__ __align__(16) f16 sA[128 * 64];
  __shared__ __align__(16) f16 sB[128 * 64];
  const f16* Hb = H + (size_t)b * CCH * NTOK;
  int k0 = split * (NTOK / SPLITS);
  f32x4 acc[4][4] = {};
  int ldsrow = wid * 8 + (lane >> 3);
  int slot = lane & 7;
  int lr = lane & 15, lk = lane >> 4;

  const int NS = (NTOK / SPLITS) / 64;
  for (int ks = 0; ks < NS; ++ks) {
    int kk0 = k0 + ks * 64;
    __syncthreads();
#pragma unroll
    for (int i = 0; i < 4; ++i) {
      int row = ldsrow + i * 32;
      int cA = ((slot ^ (row & 7)) * 8);
      g2l16(Hb + (size_t)(m0 + row) * NTOK + kk0 + cA, &sA[i * 2048 + wid * 512]);
      g2l16(Hb + (size_t)(n0 + row) * NTOK + kk0 + cA, &sB[i * 2048 + wid * 512]);
    }
    asm volatile("s_waitcnt vmcnt(0)" ::: "memory");
    __syncthreads();
#pragma unroll
    for (int kk = 0; kk < 2; ++kk) {
      f16x8 af[4], bf[4];
#pragma unroll
      for (int mi = 0; mi < 4; ++mi) {
        int row = wr * 64 + mi * 16 + lr;
        int ks8 = (kk * 4 + lk) ^ (row & 7);
        af[mi] = *(const f16x8*)&sA[row * 64 + ks8 * 8];
      }
#pragma unroll
      for (int ni = 0; ni < 4; ++ni) {
        int row = wc * 64 + ni * 16 + lr;
        int ks8 = (kk * 4 + lk) ^ (row & 7);
        bf[ni] = *(const f16x8*)&sB[row * 64 + ks8 * 8];
      }
#pragma unroll
      for (int mi = 0; mi < 4; ++mi)
#pragma unroll
        for (int ni = 0; ni < 4; ++ni)
          acc[mi][ni] = __builtin_amdgcn_mfma_f32_16x16x32_f16(af[mi], bf[ni], acc[mi][ni], 0, 0, 0);
    }
  }

  float* Gb = G + (size_t)b * CCH * CCH;
#pragma unroll
  for (int mi = 0; mi < 4; ++mi)
#pragma unroll
    for (int j = 0; j < 4; ++j) {
      int rr2 = m0 + wr * 64 + mi * 16 + lk * 4 + j;
#pragma unroll
      for (int ni = 0; ni < 4; ++ni) {
        int cc = n0 + wc * 64 + ni * 16 + lr;
        atomicAdd(&Gb[(size_t)rr2 * CCH + cc], acc[mi][ni][j]);
      }
    }
}

// ---------------- K3b: G16 = fp16(D_a X D_a + rank terms - 16384 I), both halves ----
__global__ __launch_bounds__(256) void k_symm2(const float* __restrict__ X,
                                               const float* __restrict__ avec,
                                               const float* __restrict__ bvec,
                                               const float* __restrict__ asxv,
                                               f16* __restrict__ G16) {
  const int TI6[6] = {0, 0, 0, 1, 1, 2};
  const int TJ6[6] = {1, 2, 3, 2, 3, 3};
  int bx = blockIdx.x;               // [0,24): mirror pairs; [24,40): diag subtiles
  int b = blockIdx.y;
  const float* Xb = X + (size_t)b * CCH * CCH;
  f16* Gh = G16 + (size_t)b * CCH * CCH;
  const float* av = avec + b * CCH;
  const float* bv = bvec + b * CCH;
  const float* asx = asxv + b * CCH;
  __shared__ float s[64][65];
  int t = threadIdx.x;
  int r = t >> 2, cg = (t & 3) * 16;
  int ib, jb;
  bool mirror = bx < 24;
  if (mirror) {
    int t6 = bx >> 2, sub = bx & 3;
    ib = TI6[t6] * 2 + (sub >> 1); jb = TJ6[t6] * 2 + (sub & 1);
  } else {
    int idx = bx - 24; int dt = idx >> 2, sub = idx & 3;
    ib = dt * 2 + (sub >> 1); jb = dt * 2 + (sub & 1);
  }
  int grow = ib * 64 + r, gcol0 = jb * 64 + cg;
  float ar = av[grow], br = bv[grow], asxr = asx[grow];
  const float* src = &Xb[(size_t)grow * CCH + gcol0];
  f16 hv[16] __attribute__((aligned(16)));
#pragma unroll
  for (int k = 0; k < 4; ++k) {
    float4 xv = *(const float4*)(src + k * 4);
    float vv[4] = {xv.x, xv.y, xv.z, xv.w};
#pragma unroll
    for (int i = 0; i < 4; ++i) {
      int cc = gcol0 + k * 4 + i;
      float v = ar * av[cc] * vv[i] + asxr * bv[cc] + br * asx[cc]
                + (float)NTOK * br * bv[cc];
      if (grow == cc) v -= 16384.f;
      hv[k * 4 + i] = (f16)v;
      if (mirror) s[r][cg + k * 4 + i] = v;   // symmetric expression -> same value
    }
  }
  f16* d16 = &Gh[(size_t)grow * CCH + gcol0];
  *(uint4*)&d16[0] = ((const uint4*)hv)[0];
  *(uint4*)&d16[8] = ((const uint4*)hv)[1];
  if (mirror) {
    __syncthreads();
    f16 hw[16] __attribute__((aligned(16)));
#pragma unroll
    for (int k = 0; k < 16; ++k) hw[k] = (f16)s[cg + k][r];
    f16* m16 = &Gh[(size_t)(jb * 64 + r) * CCH + ib * 64 + cg];
    *(uint4*)&m16[0] = ((const uint4*)hw)[0];
    *(uint4*)&m16[8] = ((const uint4*)hw)[1];
  }
}

// ---------------- K4: fp16 MFMA 512^3 GEMM: C[b] = A16 @ Bt16[b]^T ----------------
// CORR: +16384*corr[m][n] (restores diag shift). !CORR: *ascale[b][n] (M D_a).
template <bool CORR>
__global__ __launch_bounds__(256, 2) void k_hgemm512(const f16* __restrict__ A16,
                                                     const f16* __restrict__ Bt16,
                                                     f16* __restrict__ Cv,
                                                     const float* __restrict__ corr,
                                                     const float* __restrict__ ascale) {
  int n0 = blockIdx.x * 128, m0 = blockIdx.y * 128, b = blockIdx.z;
  int t = threadIdx.x, lane = t & 63, wid = t >> 6;
  int wr = wid >> 1, wc = wid & 1;
  __shared__ __align__(16) f16 sA[128 * 64];
  __shared__ __align__(16) f16 sB[128 * 64];
  const f16* Bp = Bt16 + (size_t)b * CCH * CCH;
  f32x4 acc[4][4] = {};
  int ldsrow = wid * 8 + (lane >> 3);
  int slot = lane & 7;
  int lr = lane & 15, lk = lane >> 4;
  for (int ks = 0; ks < 8; ++ks) {
    int kk0 = ks * 64;
    __syncthreads();
#pragma unroll
    for (int i = 0; i < 4; ++i) {
      int row = ldsrow + i * 32;
      int cA = ((slot ^ (row & 7)) * 8);
      g2l16(A16 + (size_t)(m0 + row) * CCH + kk0 + cA, &sA[i * 2048 + wid * 512]);
      g2l16(Bp + (size_t)(n0 + row) * CCH + kk0 + cA, &sB[i * 2048 + wid * 512]);
    }
    asm volatile("s_waitcnt vmcnt(0)" ::: "memory");
    __syncthreads();
#pragma unroll
    for (int kk = 0; kk < 2; ++kk) {
      f16x8 af[4], bf[4];
#pragma unroll
      for (int mi = 0; mi < 4; ++mi) {
        int row = wr * 64 + mi * 16 + lr;
        int ks8 = (kk * 4 + lk) ^ (row & 7);
        af[mi] = *(const f16x8*)&sA[row * 64 + ks8 * 8];
      }
#pragma unroll
      for (int ni = 0; ni < 4; ++ni) {
        int row = wc * 64 + ni * 16 + lr;
        int ks8 = (kk * 4 + lk) ^ (row & 7);
        bf[ni] = *(const f16x8*)&sB[row * 64 + ks8 * 8];
      }
#pragma unroll
      for (int mi = 0; mi < 4; ++mi)
#pragma unroll
        for (int ni = 0; ni < 4; ++ni)
          acc[mi][ni] = __builtin_amdgcn_mfma_f32_16x16x32_f16(af[mi], bf[ni], acc[mi][ni], 0, 0, 0);
    }
  }
#pragma unroll
  for (int mi = 0; mi < 4; ++mi)
#pragma unroll
    for (int j = 0; j < 4; ++j) {
      int o = m0 + wr * 64 + mi * 16 + lk * 4 + j;
#pragma unroll
      for (int ni = 0; ni < 4; ++ni) {
        int n = n0 + wc * 64 + ni * 16 + lr;
        float v = acc[mi][ni][j];
        if constexpr (CORR) v += 16384.f * corr[(size_t)o * CCH + n];
        else                v *= ascale[(size_t)b * CCH + n];
        Cv[(size_t)b * CCH * CCH + (size_t)o * CCH + n] = (f16)v;
      }
    }
}

// ---------------- K5: fused per-(b,h) attention ----------------
__global__ __launch_bounds__(256) void k_attn(const f16* __restrict__ T1h,
                                              const f16* __restrict__ Wqkv16,
                                              const f16* __restrict__ Wvt16,
                                              const float* __restrict__ qkvw,
                                              const float* __restrict__ qkvb,
                                              const float* __restrict__ svec,
                                              const float* __restrict__ yvec,
                                              f16* __restrict__ Rt16,
                                              float* __restrict__ pbv) {
  int h = blockIdx.x, b = blockIdx.y;
  int h64 = h * 64;
  int t = threadIdx.x, lane = t & 63, wid = t >> 6;
  int lr = lane & 15, lk = lane >> 4;
  __shared__ float ss[512];
  __shared__ float suq[64], suk[64], sbq[64], sbk[64], sbv[64];
  __shared__ float Lsm[64][68];
  __shared__ f16 Psm[64][72];

  for (int i = t; i < 512; i += 256) ss[i] = svec[b * CCH + i];
  if (t < 64) {
    sbq[t] = qkvb[h64 + t];
    sbk[t] = qkvb[512 + h64 + t];
    sbv[t] = qkvb[1024 + h64 + t] + yvec[b * CCH + h64 + t];   // + Wv@b fold
  }
  __syncthreads();
  if (t < 128) {
    int o = t & 63; bool isk = t >= 64;
    const float* wr_ = qkvw + (size_t)((isk ? 512 : 0) + h64 + o) * CCH;
    float a = 0.f;
#pragma unroll
    for (int i = 0; i < 128; ++i) {
      float4 w = *(const float4*)&wr_[i * 4];
      a += w.x * ss[i * 4] + w.y * ss[i * 4 + 1] + w.z * ss[i * 4 + 2] + w.w * ss[i * 4 + 3];
    }
    (isk ? suk : suq)[o] = a;
  }
  int wr = wid >> 1, wc = wid & 1;
  f32x4 lacc[2][2] = {};
  const f16* Ab = T1h + (size_t)b * CCH * CCH;
  const f16* Bb = Wqkv16 + (size_t)(512 + h64) * CCH;
  for (int ks = 0; ks < 16; ++ks) {
    int kq = ks * 32 + lk * 8;
    f16x8 af[2], bf[2];
#pragma unroll
    for (int mi = 0; mi < 2; ++mi)
      af[mi] = *(const f16x8*)&Ab[(size_t)(h64 + wr * 32 + mi * 16 + lr) * CCH + kq];
#pragma unroll
    for (int ni = 0; ni < 2; ++ni)
      bf[ni] = *(const f16x8*)&Bb[(size_t)(wc * 32 + ni * 16 + lr) * CCH + kq];
#pragma unroll
    for (int mi = 0; mi < 2; ++mi)
#pragma unroll
      for (int ni = 0; ni < 2; ++ni)
        lacc[mi][ni] = __builtin_amdgcn_mfma_f32_16x16x32_f16(af[mi], bf[ni], lacc[mi][ni], 0, 0, 0);
  }
  __syncthreads();
#pragma unroll
  for (int mi = 0; mi < 2; ++mi)
#pragma unroll
    for (int ni = 0; ni < 2; ++ni)
#pragma unroll
      for (int j = 0; j < 4; ++j) {
        int d = wr * 32 + mi * 16 + lk * 4 + j;
        int e = wc * 32 + ni * 16 + lr;
        Lsm[d][e] = (lacc[mi][ni][j] + suq[d] * sbk[e] + sbq[d] * suk[e]
                     + 16384.f * sbq[d] * sbk[e]) * 0.125f;
      }
  __syncthreads();
  if (t < 64) {
    float m = -1e30f;
#pragma unroll
    for (int e = 0; e < 64; ++e) m = fmaxf(m, Lsm[t][e]);
    float p[64];
    float sum = 0.f;
#pragma unroll
    for (int e = 0; e < 64; ++e) { p[e] = expf(Lsm[t][e] - m); sum += p[e]; }
    float r = 1.f / sum, pb = 0.f;
#pragma unroll
    for (int e = 0; e < 64; ++e) {
      float pv = p[e] * r;
      Psm[t][e] = (f16)pv;
      pb += pv * sbv[e];
    }
    pbv[b * CCH + h64 + t] = pb;
  }
  __syncthreads();
  f32x4 acc[4][8] = {};
  int c0w = wid * 128;
#pragma unroll
  for (int kk = 0; kk < 2; ++kk) {
    int e0 = kk * 32 + lk * 8;
    f16x8 pa[4], wb[8];
#pragma unroll
    for (int mi = 0; mi < 4; ++mi)
      pa[mi] = *(const f16x8*)&Psm[mi * 16 + lr][e0];
#pragma unroll
    for (int ni = 0; ni < 8; ++ni)
      wb[ni] = *(const f16x8*)&Wvt16[(size_t)(c0w + ni * 16 + lr) * CCH + h64 + e0];
#pragma unroll
    for (int mi = 0; mi < 4; ++mi)
#pragma unroll
      for (int ni = 0; ni < 8; ++ni)
        acc[mi][ni] = __builtin_amdgcn_mfma_f32_16x16x32_f16(pa[mi], wb[ni], acc[mi][ni], 0, 0, 0);
  }
#pragma unroll
  for (int mi = 0; mi < 4; ++mi)
#pragma unroll
    for (int ni = 0; ni < 8; ++ni) {
      int d0 = mi * 16 + lk * 4;
      int c = c0w + ni * 16 + lr;
      f16 hv[4] __attribute__((aligned(8)));
#pragma unroll
      for (int j = 0; j < 4; ++j) hv[j] = (f16)acc[mi][ni][j];
      *(uint2*)&Rt16[((size_t)b * CCH + c) * CCH + h64 + d0] = *(const uint2*)hv;
    }
}

// ---------------- K4d: cvec = out_w @ pbv + out_b (4 lanes/output) ----------------
__global__ __launch_bounds__(256) void k_cvec(const float* __restrict__ outw,
                                              const float* __restrict__ outb,
                                              const float* __restrict__ pbv,
                                              float* __restrict__ cvec) {
  int o = blockIdx.x * 64 + (threadIdx.x >> 2);   // grid.x = 8
  int l = threadIdx.x & 3;
  int b = blockIdx.y;
  __shared__ float sp[512];
  for (int i = threadIdx.x; i < 512; i += 256) sp[i] = pbv[b * CCH + i];
  __syncthreads();
  const float* wr_ = outw + (size_t)o * CCH + l * 128;
  const float* spp = sp + l * 128;
  float a = 0.f;
#pragma unroll
  for (int i = 0; i < 32; ++i) {
    float4 w = *(const float4*)&wr_[i * 4];
    a += w.x * spp[i * 4] + w.y * spp[i * 4 + 1] + w.z * spp[i * 4 + 2] + w.w * spp[i * 4 + 3];
  }
  a += __shfl_down(a, 2);
  a += __shfl_down(a, 1);
  if (l == 0) cvec[b * CCH + o] = a + outb[o];
}

// ---------------- K6: out = x + Ma16 @ x16^T + cvec (fp16 MFMA, B = xt16) ----------
__global__ __launch_bounds__(256, 2) void k_out(const f16* __restrict__ M16,
                                                const f16* __restrict__ Ht,
                                                const float* __restrict__ x,
                                                const float* __restrict__ cvec,
                                                float* __restrict__ out) {
  int nt = blockIdx.x;   // 128 n-tiles
  int mt = blockIdx.y;   // 4 o-tiles
  int b = blockIdx.z;
  int m0 = mt * 128, n0 = nt * 128;
  int t = threadIdx.x, lane = t & 63, wid = t >> 6;
  int wr = wid >> 1, wc = wid & 1;
  __shared__ __align__(16) f16 sA[128 * 64];
  __shared__ __align__(16) f16 sB[128 * 64];
  const f16* A = M16 + (size_t)b * CCH * CCH;
  const f16* Bp = Ht + (size_t)b * NTOK * CCH;
  f32x4 acc[4][4] = {};
  int ldsrow = wid * 8 + (lane >> 3);
  int slot = lane & 7;
  int lr = lane & 15, lk = lane >> 4;
  for (int ks = 0; ks < 8; ++ks) {
    int kk0 = ks * 64;
    __syncthreads();
#pragma unroll
    for (int i = 0; i < 4; ++i) {
      int row = ldsrow + i * 32;
      int cA = ((slot ^ (row & 7)) * 8);
      g2l16(A + (size_t)(m0 + row) * CCH + kk0 + cA, &sA[i * 2048 + wid * 512]);
      g2l16(Bp + (size_t)(n0 + row) * CCH + kk0 + cA, &sB[i * 2048 + wid * 512]);
    }
    asm volatile("s_waitcnt vmcnt(0)" ::: "memory");
    __syncthreads();
#pragma unroll
    for (int kk = 0; kk < 2; ++kk) {
      f16x8 af[4], bf[4];
#pragma unroll
      for (int mi = 0; mi < 4; ++mi) {
        int row = wr * 64 + mi * 16 + lr;
        int ks8 = (kk * 4 + lk) ^ (row & 7);
        af[mi] = *(const f16x8*)&sA[row * 64 + ks8 * 8];
      }
#pragma unroll
      for (int ni = 0; ni < 4; ++ni) {
        int row = wc * 64 + ni * 16 + lr;
        int ks8 = (kk * 4 + lk) ^ (row & 7);
        bf[ni] = *(const f16x8*)&sB[row * 64 + ks8 * 8];
      }
#pragma unroll
      for (int mi = 0; mi < 4; ++mi)
#pragma unroll
        for (int ni = 0; ni < 4; ++ni)   // swapped: D[n][o] fragment
          acc[mi][ni] = __builtin_amdgcn_mfma_f32_16x16x32_f16(bf[ni], af[mi], acc[mi][ni], 0, 0, 0);
    }
  }

  const float* xb = x + ((size_t)b * CCH) * NTOK;
  float* ob = out + ((size_t)b * CCH) * NTOK;
#pragma unroll
  for (int mi = 0; mi < 4; ++mi) {
    int o = m0 + wr * 64 + mi * 16 + lr;
    float cv = cvec[b * CCH + o];
    size_t rowoff = (size_t)o * NTOK;
#pragma unroll
    for (int ni = 0; ni < 4; ++ni) {
      int n = n0 + wc * 64 + ni * 16 + lk * 4;
      float4 xv = *(const float4*)&xb[rowoff + n];
      float4 ov;
      ov.x = xv.x + acc[mi][ni][0] + cv;
      ov.y = xv.y + acc[mi][ni][1] + cv;
      ov.z = xv.z + acc[mi][ni][2] + cv;
      ov.w = xv.w + acc[mi][ni][3] + cv;
      *(float4*)&ob[rowoff + n] = ov;
    }
  }
}

extern "C" void kernel_launch(void* const* d_in, const int* in_sizes, int n_in,
                              void* d_out, int out_size, void* d_ws, size_t ws_size,
                              hipStream_t stream) {
  const float* x    = (const float*)d_in[0];
  const float* gw   = (const float*)d_in[1];
  const float* gb   = (const float*)d_in[2];
  const float* qkvw = (const float*)d_in[3];
  const float* qkvb = (const float*)d_in[4];
  const float* outw = (const float*)d_in[5];
  const float* outb = (const float*)d_in[6];
  int B = in_sizes[0] / (CCH * NTOK);   // 4

  char* ws = (char*)d_ws;
  size_t off = 0;
  f16* x16    = (f16*)(ws + off);   off += (size_t)B * CCH * NTOK * 2;   // 64 MiB
  f16* xt16   = (f16*)(ws + off);   off += (size_t)B * NTOK * CCH * 2;   // 64 MiB
  float* X    = (float*)(ws + off); off += (size_t)B * CCH * CCH * 4;    // 4 MiB
  f16* G16    = (f16*)(ws + off);   off += (size_t)B * CCH * CCH * 2;    // 2 MiB
  f16* T1h    = (f16*)(ws + off);   off += (size_t)B * CCH * CCH * 2;    // 2 MiB
  f16* Rt16   = (f16*)(ws + off);   off += (size_t)B * CCH * CCH * 2;    // 2 MiB
  f16* M16    = (f16*)(ws + off);   off += (size_t)B * CCH * CCH * 2;    // 2 MiB
  f16* Wqkv16 = (f16*)(ws + off);   off += (size_t)3 * CCH * CCH * 2;    // 1.5 MiB
  f16* Ow16   = (f16*)(ws + off);   off += (size_t)CCH * CCH * 2;        // 0.5 MiB
  f16* Wvt16  = (f16*)(ws + off);   off += (size_t)CCH * CCH * 2;        // 0.5 MiB
  float* avec = (float*)(ws + off); off += (size_t)B * CCH * 4;
  float* bvec = (float*)(ws + off); off += (size_t)B * CCH * 4;
  float* asxv = (float*)(ws + off); off += (size_t)B * CCH * 4;
  float* svecH= (float*)(ws + off); off += (size_t)B * CCH * 4;
  float* yvec = (float*)(ws + off); off += (size_t)B * CCH * 4;
  float* pbv  = (float*)(ws + off); off += (size_t)B * CCH * 4;
  float* cvec = (float*)(ws + off); off += (size_t)B * CCH * 4;
  // zero-init region: stats, sx (contiguous -> single memset)
  float* stats = (float*)(ws + off); off += (size_t)B * 8 * 2 * 4;
  float* sx    = (float*)(ws + off); off += (size_t)B * CCH * 4;
  size_t zbytes = (size_t)(B * 8 * 2 + B * CCH) * 4;

  hipMemsetAsync(X, 0, (size_t)B * CCH * CCH * 4, stream);
  hipMemsetAsync(stats, 0, zbytes, stream);

  k_prep2<<<dim3(3136), 256, 0, stream>>>(x, stats, sx, x16, xt16,
                                          qkvw, Wqkv16, outw, Ow16, Wvt16);
  k_ab<<<dim3(8, B), 256, 0, stream>>>(stats, gw, gb, sx, qkvw,
                                       avec, bvec, asxv, svecH, yvec);
  k_syrk<<<dim3(10, SPLITS, B), 256, 0, stream>>>(x16, X);
  k_symm2<<<dim3(40, B), 256, 0, stream>>>(X, avec, bvec, asxv, G16);
  k_hgemm512<true><<<dim3(4, 4, B), 256, 0, stream>>>(Wqkv16, G16, T1h, qkvw, nullptr);
  k_attn<<<dim3(NHEAD, B), 256, 0, stream>>>(T1h, Wqkv16, Wvt16, qkvw, qkvb,
                                             svecH, yvec, Rt16, pbv);
  k_hgemm512<false><<<dim3(4, 4, B), 256, 0, stream>>>(Ow16, Rt16, M16, nullptr, avec);
  k_cvec<<<dim3(8, B), 256, 0, stream>>>(outw, outb, pbv, cvec);
  k_out<<<dim3(128, 4, B), 256, 0, stream>>>(M16, xt16, x, cvec, (float*)d_out);
}

// Round 20
// 267.985 us; speedup vs baseline: 1.2043x; 1.0344x over previous
//
#include <hip/hip_runtime.h>
#include <hip/hip_fp16.h>

// AttentionBlock3D: channel attention. B=4, C=512, N=T*H*W=16384, 8 heads, d=64.
// R19 formulation: GroupNorm folded algebraically (H = D_a x + b 1^T never
// materialized):
//   X = x16 x16^T (syrk on fp16-cast x), sx = x 1,
//   G_H = D_a X D_a + asx b^T + b asx^T + N b b^T  (applied in k_symm2 cast),
//   logits chain via G16 = fp16(G_H - 16384 I) + exact fp32 restore,
//   M H = (M D_a) x + (M b) 1^T: k_out uses Ma16 (col-scaled) x xt16; M b folds
//   into pbv via bv += Wv b inside k_attn.
// R20: k_out residual read uses x16 (fp16 copy of x, already produced by prep2)
//   instead of fp32 x: -64MB fetch demand; adds <=0.002 abs output error.
// MFMA geometry LOCKED (R9): BK=64, XOR-swizzle slot^(row&7), 0 bank conflicts,
//   single 32KB LDS, 2 barriers/K-step, lb(256,2). k_out K-loop frozen.
// R17 LESSON: software-barrier mega-fusion regressed (2.7% occupancy);
//   graph-replayed small launches win for <=64-block phases.

#define CCH 512
#define NTOK 16384
#define NHEAD 8

typedef _Float16 f16;
typedef _Float16 f16x8 __attribute__((ext_vector_type(8)));
typedef float f32x4 __attribute__((ext_vector_type(4)));

__device__ __forceinline__ void g2l16(const void* g, void* l) {
  __builtin_amdgcn_global_load_lds((const __attribute__((address_space(1))) void*)g,
                                   (__attribute__((address_space(3))) void*)l,
                                   16, 0, 0);
}

// ---------------- K1: one pass over x + weight casts ----------------
__global__ __launch_bounds__(256) void k_prep2(const float* __restrict__ x,
                                               float* __restrict__ stats,
                                               float* __restrict__ sx,
                                               f16* __restrict__ x16,
                                               f16* __restrict__ xt16,
                                               const float* __restrict__ qkvw,
                                               f16* __restrict__ Wqkv16,
                                               const float* __restrict__ outw,
                                               f16* __restrict__ Ow16,
                                               f16* __restrict__ Wvt16) {
  __shared__ __align__(16) char smp[34816];
  int bid = blockIdx.x;
  int t = threadIdx.x;
  if (bid < 2048) {                      // ---- x pass ----
    f16 (*T2)[260] = (f16(*)[260])smp;            // 33280 B
    float (*svp)[64] = (float(*)[64])(smp + 33280); // 1024 B
    float* lsq = (float*)(smp + 34304);            // 8 floats
    int nc = bid & 63, cg = (bid >> 6) & 7, b = bid >> 9;
    int c0 = cg * 64, n0 = nc * 256;
    int tq = t & 63, rr0 = t >> 6;
    float s = 0.f, q = 0.f;
#pragma unroll
    for (int it = 0; it < 16; ++it) {
      int r = it * 4 + rr0;
      int c = c0 + r;
      size_t idx = ((size_t)(b * CCH + c)) * NTOK + n0 + tq * 4;
      float4 xv = *(const float4*)&x[idx];
      s += xv.x + xv.y + xv.z + xv.w;
      q += xv.x * xv.x + xv.y * xv.y + xv.z * xv.z + xv.w * xv.w;
      f16 hh[4] __attribute__((aligned(8)));
      hh[0] = (f16)xv.x; hh[1] = (f16)xv.y; hh[2] = (f16)xv.z; hh[3] = (f16)xv.w;
      *(uint2*)&x16[idx] = *(const uint2*)hh;
      *(uint2*)&T2[r][tq * 4] = *(const uint2*)hh;
    }
    for (int off = 32; off; off >>= 1) { s += __shfl_down(s, off); q += __shfl_down(q, off); }
    int wid = t >> 6, lane = t & 63;
    if (lane == 0) { lsq[wid] = s; lsq[4 + wid] = q; }
    __syncthreads();
    if (t == 0) {
      atomicAdd(&stats[(b * 8 + cg) * 2 + 0], lsq[0] + lsq[1] + lsq[2] + lsq[3]);
      atomicAdd(&stats[(b * 8 + cg) * 2 + 1], lsq[4] + lsq[5] + lsq[6] + lsq[7]);
    }
    {
      int c = t & 63, qd = t >> 6;
      float acc = 0.f;
#pragma unroll
      for (int j = 0; j < 64; ++j) acc += (float)T2[c][qd * 64 + j];
      svp[qd][c] = acc;
    }
    __syncthreads();
    if (t < 64) {
      atomicAdd(&sx[b * CCH + c0 + t],
                svp[0][t] + svp[1][t] + svp[2][t] + svp[3][t]);
    }
    int s8 = t & 7, nl = t >> 3;
#pragma unroll
    for (int it = 0; it < 8; ++it) {
      int n = it * 32 + nl;
      f16 g[8] __attribute__((aligned(16)));
#pragma unroll
      for (int j = 0; j < 8; ++j) g[j] = T2[s8 * 8 + j][n];
      *(uint4*)&xt16[((size_t)b * NTOK + n0 + n) * CCH + c0 + s8 * 8] = *(const uint4*)g;
    }
  } else if (bid < 3072) {               // ---- weight casts ----
    int bid2 = bid - 2048;
    bool isB = bid2 >= 768;
    int i = (isB ? (bid2 - 768) : bid2) * 256 + t;
    const float* src = isB ? outw : qkvw;
    f16* dst = isB ? Ow16 : Wqkv16;
    float4 v = *(const float4*)&src[i * 4];
    f16 h[4] __attribute__((aligned(8)));
    h[0] = (f16)v.x; h[1] = (f16)v.y; h[2] = (f16)v.z; h[3] = (f16)v.w;
    *(uint2*)&dst[i * 4] = *(const uint2*)h;
  } else {                               // ---- Wv transpose-cast ----
    int j = bid - 3072;
    int et = j >> 3, ct = j & 7;
    f16 (*tl)[72] = (f16(*)[72])smp;
    int r = t >> 2, cq = (t & 3) * 16;
    const float* src = &qkvw[(size_t)(1024 + et * 64 + r) * CCH + ct * 64 + cq];
#pragma unroll
    for (int k = 0; k < 4; ++k) {
      float4 v = *(const float4*)(src + k * 4);
      tl[r][cq + k * 4 + 0] = (f16)v.x; tl[r][cq + k * 4 + 1] = (f16)v.y;
      tl[r][cq + k * 4 + 2] = (f16)v.z; tl[r][cq + k * 4 + 3] = (f16)v.w;
    }
    __syncthreads();
    f16 hv[16] __attribute__((aligned(16)));
#pragma unroll
    for (int jj = 0; jj < 16; ++jj) hv[jj] = tl[cq + jj][r];
    f16* dst = &Wvt16[(size_t)(ct * 64 + r) * CCH + et * 64 + cq];
    *(uint4*)&dst[0] = ((const uint4*)hv)[0];
    *(uint4*)&dst[8] = ((const uint4*)hv)[1];
  }
}

// ---------------- K2: per-batch GN vectors + y = Wv @ b ----------------
__global__ __launch_bounds__(256) void k_ab(const float* __restrict__ stats,
                                            const float* __restrict__ gw,
                                            const float* __restrict__ gb,
                                            const float* __restrict__ sx,
                                            const float* __restrict__ qkvw,
                                            float* __restrict__ avec,
                                            float* __restrict__ bvec,
                                            float* __restrict__ asxv,
                                            float* __restrict__ svecH,
                                            float* __restrict__ yvec) {
  int ob = blockIdx.x, b = blockIdx.y;
  int t = threadIdx.x;
  __shared__ float smean[8], srsig[8], sb[512];
  if (t < 8) {
    const float inv = 1.f / (64.f * (float)NTOK);
    float sum = stats[(b * 8 + t) * 2], sq = stats[(b * 8 + t) * 2 + 1];
    float mean = sum * inv;
    float var = fmaxf(sq * inv - mean * mean, 0.f);
    smean[t] = mean; srsig[t] = rsqrtf(var + 1e-5f);
  }
  __syncthreads();
  for (int c = t; c < 512; c += 256) {
    int g = c >> 6;
    float a = gw[c] * srsig[g];
    sb[c] = gb[c] - smean[g] * a;
  }
  __syncthreads();
  if (t < 64) {
    int c = ob * 64 + t; int g = c >> 6;
    float a = gw[c] * srsig[g];
    float bb = sb[c];
    float sxc = sx[b * CCH + c];
    avec[b * CCH + c] = a;
    bvec[b * CCH + c] = bb;
    asxv[b * CCH + c] = a * sxc;
    svecH[b * CCH + c] = a * sxc + (float)NTOK * bb;
  }
  int e = ob * 64 + (t >> 2);
  int l = t & 3;
  const float* wr_ = qkvw + (size_t)(1024 + e) * CCH + l * 128;
  const float* sbb = sb + l * 128;
  float acc = 0.f;
#pragma unroll
  for (int i = 0; i < 32; ++i) {
    float4 w = *(const float4*)&wr_[i * 4];
    acc += w.x * sbb[i * 4] + w.y * sbb[i * 4 + 1] + w.z * sbb[i * 4 + 2] + w.w * sbb[i * 4 + 3];
  }
  acc += __shfl_down(acc, 2);
  acc += __shfl_down(acc, 1);
  if (l == 0) yvec[b * CCH + e] = acc;
}

// ---------------- K3: X = x16 x16^T, upper tiles, split-K=16, BK=64 (32KB) ----
#define SPLITS 16
__global__ __launch_bounds__(256, 2) void k_syrk(const f16* __restrict__ H,
                                                 float* __restrict__ G) {
  const int TI[10] = {0, 0, 0, 0, 1, 1, 1, 2, 2, 3};
  const int TJ[10] = {0, 1, 2, 3, 1, 2, 3, 2, 3, 3};
  int tile = blockIdx.x;
  int split = blockIdx.y;
  int b = blockIdx.z;
  int ii = TI[tile], jj = TJ[tile];
  int m0 = ii * 128, n0 = jj * 128;
  int t = threadIdx.x, lane = t & 63, wid = t >> 6;
  int wr = wid >> 1, wc = wid & 1;
  __shared__ __align__(16) f16 sA[128 * 64];
  __shared__ __align__(16) f16 sB[128 * 64];
  const f16* Hb = H + (size_t)b * CCH * NTOK;
  int k0 = split * (NTOK / SPLITS);
  f32x4 acc[4][4] = {};
  int ldsrow = wid * 8 + (lane >> 3);
  int slot = lane & 7;
  int lr = lane & 15, lk = lane >> 4;

  const int NS = (NTOK / SPLITS) / 64;
  for (int ks = 0; ks < NS; ++ks) {
    int kk0 = k0 + ks * 64;
    __syncthreads();
#pragma unroll
    for (int i = 0; i < 4; ++i) {
      int row = ldsrow + i * 32;
      int cA = ((slot ^ (row & 7)) * 8);
      g2l16(Hb + (size_t)(m0 + row) * NTOK + kk0 + cA, &sA[i * 2048 + wid * 512]);
      g2l16(Hb + (size_t)(n0 + row) * NTOK + kk0 + cA, &sB[i * 2048 + wid * 512]);
    }
    asm volatile("s_waitcnt vmcnt(0)" ::: "memory");
    __syncthreads();
#pragma unroll
    for (int kk = 0; kk < 2; ++kk) {
      f16x8 af[4], bf[4];
#pragma unroll
      for (int mi = 0; mi < 4; ++mi) {
        int row = wr * 64 + mi * 16 + lr;
        int ks8 = (kk * 4 + lk) ^ (row & 7);
        af[mi] = *(const f16x8*)&sA[row * 64 + ks8 * 8];
      }
#pragma unroll
      for (int ni = 0; ni < 4; ++ni) {
        int row = wc * 64 + ni * 16 + lr;
        int ks8 = (kk * 4 + lk) ^ (row & 7);
        bf[ni] = *(const f16x8*)&sB[row * 64 + ks8 * 8];
      }
#pragma unroll
      for (int mi = 0; mi < 4; ++mi)
#pragma unroll
        for (int ni = 0; ni < 4; ++ni)
          acc[mi][ni] = __builtin_amdgcn_mfma_f32_16x16x32_f16(af[mi], bf[ni], acc[mi][ni], 0, 0, 0);
    }
  }

  float* Gb = G + (size_t)b * CCH * CCH;
#pragma unroll
  for (int mi = 0; mi < 4; ++mi)
#pragma unroll
    for (int j = 0; j < 4; ++j) {
      int rr2 = m0 + wr * 64 + mi * 16 + lk * 4 + j;
#pragma unroll
      for (int ni = 0; ni < 4; ++ni) {
        int cc = n0 + wc * 64 + ni * 16 + lr;
        atomicAdd(&Gb[(size_t)rr2 * CCH + cc], acc[mi][ni][j]);
      }
    }
}

// ---------------- K3b: G16 = fp16(D_a X D_a + rank terms - 16384 I), both halves ----
__global__ __launch_bounds__(256) void k_symm2(const float* __restrict__ X,
                                               const float* __restrict__ avec,
                                               const float* __restrict__ bvec,
                                               const float* __restrict__ asxv,
                                               f16* __restrict__ G16) {
  const int TI6[6] = {0, 0, 0, 1, 1, 2};
  const int TJ6[6] = {1, 2, 3, 2, 3, 3};
  int bx = blockIdx.x;
  int b = blockIdx.y;
  const float* Xb = X + (size_t)b * CCH * CCH;
  f16* Gh = G16 + (size_t)b * CCH * CCH;
  const float* av = avec + b * CCH;
  const float* bv = bvec + b * CCH;
  const float* asx = asxv + b * CCH;
  __shared__ float s[64][65];
  int t = threadIdx.x;
  int r = t >> 2, cg = (t & 3) * 16;
  int ib, jb;
  bool mirror = bx < 24;
  if (mirror) {
    int t6 = bx >> 2, sub = bx & 3;
    ib = TI6[t6] * 2 + (sub >> 1); jb = TJ6[t6] * 2 + (sub & 1);
  } else {
    int idx = bx - 24; int dt = idx >> 2, sub = idx & 3;
    ib = dt * 2 + (sub >> 1); jb = dt * 2 + (sub & 1);
  }
  int grow = ib * 64 + r, gcol0 = jb * 64 + cg;
  float ar = av[grow], br = bv[grow], asxr = asx[grow];
  const float* src = &Xb[(size_t)grow * CCH + gcol0];
  f16 hv[16] __attribute__((aligned(16)));
#pragma unroll
  for (int k = 0; k < 4; ++k) {
    float4 xv = *(const float4*)(src + k * 4);
    float vv[4] = {xv.x, xv.y, xv.z, xv.w};
#pragma unroll
    for (int i = 0; i < 4; ++i) {
      int cc = gcol0 + k * 4 + i;
      float v = ar * av[cc] * vv[i] + asxr * bv[cc] + br * asx[cc]
                + (float)NTOK * br * bv[cc];
      if (grow == cc) v -= 16384.f;
      hv[k * 4 + i] = (f16)v;
      if (mirror) s[r][cg + k * 4 + i] = v;
    }
  }
  f16* d16 = &Gh[(size_t)grow * CCH + gcol0];
  *(uint4*)&d16[0] = ((const uint4*)hv)[0];
  *(uint4*)&d16[8] = ((const uint4*)hv)[1];
  if (mirror) {
    __syncthreads();
    f16 hw[16] __attribute__((aligned(16)));
#pragma unroll
    for (int k = 0; k < 16; ++k) hw[k] = (f16)s[cg + k][r];
    f16* m16 = &Gh[(size_t)(jb * 64 + r) * CCH + ib * 64 + cg];
    *(uint4*)&m16[0] = ((const uint4*)hw)[0];
    *(uint4*)&m16[8] = ((const uint4*)hw)[1];
  }
}

// ---------------- K4: fp16 MFMA 512^3 GEMM: C[b] = A16 @ Bt16[b]^T ----------------
template <bool CORR>
__global__ __launch_bounds__(256, 2) void k_hgemm512(const f16* __restrict__ A16,
                                                     const f16* __restrict__ Bt16,
                                                     f16* __restrict__ Cv,
                                                     const float* __restrict__ corr,
                                                     const float* __restrict__ ascale) {
  int n0 = blockIdx.x * 128, m0 = blockIdx.y * 128, b = blockIdx.z;
  int t = threadIdx.x, lane = t & 63, wid = t >> 6;
  int wr = wid >> 1, wc = wid & 1;
  __shared__ __align__(16) f16 sA[128 * 64];
  __shared__ __align__(16) f16 sB[128 * 64];
  const f16* Bp = Bt16 + (size_t)b * CCH * CCH;
  f32x4 acc[4][4] = {};
  int ldsrow = wid * 8 + (lane >> 3);
  int slot = lane & 7;
  int lr = lane & 15, lk = lane >> 4;
  for (int ks = 0; ks < 8; ++ks) {
    int kk0 = ks * 64;
    __syncthreads();
#pragma unroll
    for (int i = 0; i < 4; ++i) {
      int row = ldsrow + i * 32;
      int cA = ((slot ^ (row & 7)) * 8);
      g2l16(A16 + (size_t)(m0 + row) * CCH + kk0 + cA, &sA[i * 2048 + wid * 512]);
      g2l16(Bp + (size_t)(n0 + row) * CCH + kk0 + cA, &sB[i * 2048 + wid * 512]);
    }
    asm volatile("s_waitcnt vmcnt(0)" ::: "memory");
    __syncthreads();
#pragma unroll
    for (int kk = 0; kk < 2; ++kk) {
      f16x8 af[4], bf[4];
#pragma unroll
      for (int mi = 0; mi < 4; ++mi) {
        int row = wr * 64 + mi * 16 + lr;
        int ks8 = (kk * 4 + lk) ^ (row & 7);
        af[mi] = *(const f16x8*)&sA[row * 64 + ks8 * 8];
      }
#pragma unroll
      for (int ni = 0; ni < 4; ++ni) {
        int row = wc * 64 + ni * 16 + lr;
        int ks8 = (kk * 4 + lk) ^ (row & 7);
        bf[ni] = *(const f16x8*)&sB[row * 64 + ks8 * 8];
      }
#pragma unroll
      for (int mi = 0; mi < 4; ++mi)
#pragma unroll
        for (int ni = 0; ni < 4; ++ni)
          acc[mi][ni] = __builtin_amdgcn_mfma_f32_16x16x32_f16(af[mi], bf[ni], acc[mi][ni], 0, 0, 0);
    }
  }
#pragma unroll
  for (int mi = 0; mi < 4; ++mi)
#pragma unroll
    for (int j = 0; j < 4; ++j) {
      int o = m0 + wr * 64 + mi * 16 + lk * 4 + j;
#pragma unroll
      for (int ni = 0; ni < 4; ++ni) {
        int n = n0 + wc * 64 + ni * 16 + lr;
        float v = acc[mi][ni][j];
        if constexpr (CORR) v += 16384.f * corr[(size_t)o * CCH + n];
        else                v *= ascale[(size_t)b * CCH + n];
        Cv[(size_t)b * CCH * CCH + (size_t)o * CCH + n] = (f16)v;
      }
    }
}

// ---------------- K5: fused per-(b,h) attention ----------------
__global__ __launch_bounds__(256) void k_attn(const f16* __restrict__ T1h,
                                              const f16* __restrict__ Wqkv16,
                                              const f16* __restrict__ Wvt16,
                                              const float* __restrict__ qkvw,
                                              const float* __restrict__ qkvb,
                                              const float* __restrict__ svec,
                                              const float* __restrict__ yvec,
                                              f16* __restrict__ Rt16,
                                              float* __restrict__ pbv) {
  int h = blockIdx.x, b = blockIdx.y;
  int h64 = h * 64;
  int t = threadIdx.x, lane = t & 63, wid = t >> 6;
  int lr = lane & 15, lk = lane >> 4;
  __shared__ float ss[512];
  __shared__ float suq[64], suk[64], sbq[64], sbk[64], sbv[64];
  __shared__ float Lsm[64][68];
  __shared__ f16 Psm[64][72];

  for (int i = t; i < 512; i += 256) ss[i] = svec[b * CCH + i];
  if (t < 64) {
    sbq[t] = qkvb[h64 + t];
    sbk[t] = qkvb[512 + h64 + t];
    sbv[t] = qkvb[1024 + h64 + t] + yvec[b * CCH + h64 + t];
  }
  __syncthreads();
  if (t < 128) {
    int o = t & 63; bool isk = t >= 64;
    const float* wr_ = qkvw + (size_t)((isk ? 512 : 0) + h64 + o) * CCH;
    float a = 0.f;
#pragma unroll
    for (int i = 0; i < 128; ++i) {
      float4 w = *(const float4*)&wr_[i * 4];
      a += w.x * ss[i * 4] + w.y * ss[i * 4 + 1] + w.z * ss[i * 4 + 2] + w.w * ss[i * 4 + 3];
    }
    (isk ? suk : suq)[o] = a;
  }
  int wr = wid >> 1, wc = wid & 1;
  f32x4 lacc[2][2] = {};
  const f16* Ab = T1h + (size_t)b * CCH * CCH;
  const f16* Bb = Wqkv16 + (size_t)(512 + h64) * CCH;
  for (int ks = 0; ks < 16; ++ks) {
    int kq = ks * 32 + lk * 8;
    f16x8 af[2], bf[2];
#pragma unroll
    for (int mi = 0; mi < 2; ++mi)
      af[mi] = *(const f16x8*)&Ab[(size_t)(h64 + wr * 32 + mi * 16 + lr) * CCH + kq];
#pragma unroll
    for (int ni = 0; ni < 2; ++ni)
      bf[ni] = *(const f16x8*)&Bb[(size_t)(wc * 32 + ni * 16 + lr) * CCH + kq];
#pragma unroll
    for (int mi = 0; mi < 2; ++mi)
#pragma unroll
      for (int ni = 0; ni < 2; ++ni)
        lacc[mi][ni] = __builtin_amdgcn_mfma_f32_16x16x32_f16(af[mi], bf[ni], lacc[mi][ni], 0, 0, 0);
  }
  __syncthreads();
#pragma unroll
  for (int mi = 0; mi < 2; ++mi)
#pragma unroll
    for (int ni = 0; ni < 2; ++ni)
#pragma unroll
      for (int j = 0; j < 4; ++j) {
        int d = wr * 32 + mi * 16 + lk * 4 + j;
        int e = wc * 32 + ni * 16 + lr;
        Lsm[d][e] = (lacc[mi][ni][j] + suq[d] * sbk[e] + sbq[d] * suk[e]
                     + 16384.f * sbq[d] * sbk[e]) * 0.125f;
      }
  __syncthreads();
  if (t < 64) {
    float m = -1e30f;
#pragma unroll
    for (int e = 0; e < 64; ++e) m = fmaxf(m, Lsm[t][e]);
    float p[64];
    float sum = 0.f;
#pragma unroll
    for (int e = 0; e < 64; ++e) { p[e] = expf(Lsm[t][e] - m); sum += p[e]; }
    float r = 1.f / sum, pb = 0.f;
#pragma unroll
    for (int e = 0; e < 64; ++e) {
      float pv = p[e] * r;
      Psm[t][e] = (f16)pv;
      pb += pv * sbv[e];
    }
    pbv[b * CCH + h64 + t] = pb;
  }
  __syncthreads();
  f32x4 acc[4][8] = {};
  int c0w = wid * 128;
#pragma unroll
  for (int kk = 0; kk < 2; ++kk) {
    int e0 = kk * 32 + lk * 8;
    f16x8 pa[4], wb[8];
#pragma unroll
    for (int mi = 0; mi < 4; ++mi)
      pa[mi] = *(const f16x8*)&Psm[mi * 16 + lr][e0];
#pragma unroll
    for (int ni = 0; ni < 8; ++ni)
      wb[ni] = *(const f16x8*)&Wvt16[(size_t)(c0w + ni * 16 + lr) * CCH + h64 + e0];
#pragma unroll
    for (int mi = 0; mi < 4; ++mi)
#pragma unroll
      for (int ni = 0; ni < 8; ++ni)
        acc[mi][ni] = __builtin_amdgcn_mfma_f32_16x16x32_f16(pa[mi], wb[ni], acc[mi][ni], 0, 0, 0);
  }
#pragma unroll
  for (int mi = 0; mi < 4; ++mi)
#pragma unroll
    for (int ni = 0; ni < 8; ++ni) {
      int d0 = mi * 16 + lk * 4;
      int c = c0w + ni * 16 + lr;
      f16 hv[4] __attribute__((aligned(8)));
#pragma unroll
      for (int j = 0; j < 4; ++j) hv[j] = (f16)acc[mi][ni][j];
      *(uint2*)&Rt16[((size_t)b * CCH + c) * CCH + h64 + d0] = *(const uint2*)hv;
    }
}

// ---------------- K4d: cvec = out_w @ pbv + out_b (4 lanes/output) ----------------
__global__ __launch_bounds__(256) void k_cvec(const float* __restrict__ outw,
                                              const float* __restrict__ outb,
                                              const float* __restrict__ pbv,
                                              float* __restrict__ cvec) {
  int o = blockIdx.x * 64 + (threadIdx.x >> 2);   // grid.x = 8
  int l = threadIdx.x & 3;
  int b = blockIdx.y;
  __shared__ float sp[512];
  for (int i = threadIdx.x; i < 512; i += 256) sp[i] = pbv[b * CCH + i];
  __syncthreads();
  const float* wr_ = outw + (size_t)o * CCH + l * 128;
  const float* spp = sp + l * 128;
  float a = 0.f;
#pragma unroll
  for (int i = 0; i < 32; ++i) {
    float4 w = *(const float4*)&wr_[i * 4];
    a += w.x * spp[i * 4] + w.y * spp[i * 4 + 1] + w.z * spp[i * 4 + 2] + w.w * spp[i * 4 + 3];
  }
  a += __shfl_down(a, 2);
  a += __shfl_down(a, 1);
  if (l == 0) cvec[b * CCH + o] = a + outb[o];
}

// ---------------- K6: out = x16 + Ma16 @ x16^T + cvec (fp16 MFMA, B = xt16) --------
// R20: residual read from x16 (fp16) instead of fp32 x: -64MB fetch demand,
// adds <=~0.002 absolute output error (fp16 ulp of x ~ N(0,1)).
__global__ __launch_bounds__(256, 2) void k_out(const f16* __restrict__ M16,
                                                const f16* __restrict__ Ht,
                                                const f16* __restrict__ x16,
                                                const float* __restrict__ cvec,
                                                float* __restrict__ out) {
  int nt = blockIdx.x;   // 128 n-tiles
  int mt = blockIdx.y;   // 4 o-tiles
  int b = blockIdx.z;
  int m0 = mt * 128, n0 = nt * 128;
  int t = threadIdx.x, lane = t & 63, wid = t >> 6;
  int wr = wid >> 1, wc = wid & 1;
  __shared__ __align__(16) f16 sA[128 * 64];
  __shared__ __align__(16) f16 sB[128 * 64];
  const f16* A = M16 + (size_t)b * CCH * CCH;
  const f16* Bp = Ht + (size_t)b * NTOK * CCH;
  f32x4 acc[4][4] = {};
  int ldsrow = wid * 8 + (lane >> 3);
  int slot = lane & 7;
  int lr = lane & 15, lk = lane >> 4;
  for (int ks = 0; ks < 8; ++ks) {
    int kk0 = ks * 64;
    __syncthreads();
#pragma unroll
    for (int i = 0; i < 4; ++i) {
      int row = ldsrow + i * 32;
      int cA = ((slot ^ (row & 7)) * 8);
      g2l16(A + (size_t)(m0 + row) * CCH + kk0 + cA, &sA[i * 2048 + wid * 512]);
      g2l16(Bp + (size_t)(n0 + row) * CCH + kk0 + cA, &sB[i * 2048 + wid * 512]);
    }
    asm volatile("s_waitcnt vmcnt(0)" ::: "memory");
    __syncthreads();
#pragma unroll
    for (int kk = 0; kk < 2; ++kk) {
      f16x8 af[4], bf[4];
#pragma unroll
      for (int mi = 0; mi < 4; ++mi) {
        int row = wr * 64 + mi * 16 + lr;
        int ks8 = (kk * 4 + lk) ^ (row & 7);
        af[mi] = *(const f16x8*)&sA[row * 64 + ks8 * 8];
      }
#pragma unroll
      for (int ni = 0; ni < 4; ++ni) {
        int row = wc * 64 + ni * 16 + lr;
        int ks8 = (kk * 4 + lk) ^ (row & 7);
        bf[ni] = *(const f16x8*)&sB[row * 64 + ks8 * 8];
      }
#pragma unroll
      for (int mi = 0; mi < 4; ++mi)
#pragma unroll
        for (int ni = 0; ni < 4; ++ni)   // swapped: D[n][o] fragment
          acc[mi][ni] = __builtin_amdgcn_mfma_f32_16x16x32_f16(bf[ni], af[mi], acc[mi][ni], 0, 0, 0);
    }
  }

  const f16* xb = x16 + ((size_t)b * CCH) * NTOK;
  float* ob = out + ((size_t)b * CCH) * NTOK;
#pragma unroll
  for (int mi = 0; mi < 4; ++mi) {
    int o = m0 + wr * 64 + mi * 16 + lr;
    float cv = cvec[b * CCH + o];
    size_t rowoff = (size_t)o * NTOK;
#pragma unroll
    for (int ni = 0; ni < 4; ++ni) {
      int n = n0 + wc * 64 + ni * 16 + lk * 4;
      f16 xv[4] __attribute__((aligned(8)));
      *(uint2*)xv = *(const uint2*)&xb[rowoff + n];
      float4 ov;
      ov.x = (float)xv[0] + acc[mi][ni][0] + cv;
      ov.y = (float)xv[1] + acc[mi][ni][1] + cv;
      ov.z = (float)xv[2] + acc[mi][ni][2] + cv;
      ov.w = (float)xv[3] + acc[mi][ni][3] + cv;
      *(float4*)&ob[rowoff + n] = ov;
    }
  }
}

extern "C" void kernel_launch(void* const* d_in, const int* in_sizes, int n_in,
                              void* d_out, int out_size, void* d_ws, size_t ws_size,
                              hipStream_t stream) {
  const float* x    = (const float*)d_in[0];
  const float* gw   = (const float*)d_in[1];
  const float* gb   = (const float*)d_in[2];
  const float* qkvw = (const float*)d_in[3];
  const float* qkvb = (const float*)d_in[4];
  const float* outw = (const float*)d_in[5];
  const float* outb = (const float*)d_in[6];
  int B = in_sizes[0] / (CCH * NTOK);   // 4

  char* ws = (char*)d_ws;
  size_t off = 0;
  f16* x16    = (f16*)(ws + off);   off += (size_t)B * CCH * NTOK * 2;   // 64 MiB
  f16* xt16   = (f16*)(ws + off);   off += (size_t)B * NTOK * CCH * 2;   // 64 MiB
  float* X    = (float*)(ws + off); off += (size_t)B * CCH * CCH * 4;    // 4 MiB
  f16* G16    = (f16*)(ws + off);   off += (size_t)B * CCH * CCH * 2;    // 2 MiB
  f16* T1h    = (f16*)(ws + off);   off += (size_t)B * CCH * CCH * 2;    // 2 MiB
  f16* Rt16   = (f16*)(ws + off);   off += (size_t)B * CCH * CCH * 2;    // 2 MiB
  f16* M16    = (f16*)(ws + off);   off += (size_t)B * CCH * CCH * 2;    // 2 MiB
  f16* Wqkv16 = (f16*)(ws + off);   off += (size_t)3 * CCH * CCH * 2;    // 1.5 MiB
  f16* Ow16   = (f16*)(ws + off);   off += (size_t)CCH * CCH * 2;        // 0.5 MiB
  f16* Wvt16  = (f16*)(ws + off);   off += (size_t)CCH * CCH * 2;        // 0.5 MiB
  float* avec = (float*)(ws + off); off += (size_t)B * CCH * 4;
  float* bvec = (float*)(ws + off); off += (size_t)B * CCH * 4;
  float* asxv = (float*)(ws + off); off += (size_t)B * CCH * 4;
  float* svecH= (float*)(ws + off); off += (size_t)B * CCH * 4;
  float* yvec = (float*)(ws + off); off += (size_t)B * CCH * 4;
  float* pbv  = (float*)(ws + off); off += (size_t)B * CCH * 4;
  float* cvec = (float*)(ws + off); off += (size_t)B * CCH * 4;
  // zero-init region: stats, sx (contiguous -> single memset)
  float* stats = (float*)(ws + off); off += (size_t)B * 8 * 2 * 4;
  float* sx    = (float*)(ws + off); off += (size_t)B * CCH * 4;
  size_t zbytes = (size_t)(B * 8 * 2 + B * CCH) * 4;

  hipMemsetAsync(X, 0, (size_t)B * CCH * CCH * 4, stream);
  hipMemsetAsync(stats, 0, zbytes, stream);

  k_prep2<<<dim3(3136), 256, 0, stream>>>(x, stats, sx, x16, xt16,
                                          qkvw, Wqkv16, outw, Ow16, Wvt16);
  k_ab<<<dim3(8, B), 256, 0, stream>>>(stats, gw, gb, sx, qkvw,
                                       avec, bvec, asxv, svecH, yvec);
  k_syrk<<<dim3(10, SPLITS, B), 256, 0, stream>>>(x16, X);
  k_symm2<<<dim3(40, B), 256, 0, stream>>>(X, avec, bvec, asxv, G16);
  k_hgemm512<true><<<dim3(4, 4, B), 256, 0, stream>>>(Wqkv16, G16, T1h, qkvw, nullptr);
  k_attn<<<dim3(NHEAD, B), 256, 0, stream>>>(T1h, Wqkv16, Wvt16, qkvw, qkvb,
                                             svecH, yvec, Rt16, pbv);
  k_hgemm512<false><<<dim3(4, 4, B), 256, 0, stream>>>(Ow16, Rt16, M16, nullptr, avec);
  k_cvec<<<dim3(8, B), 256, 0, stream>>>(outw, outb, pbv, cvec);
  k_out<<<dim3(128, 4, B), 256, 0, stream>>>(M16, xt16, x16, cvec, (float*)d_out);
}